// Round 8
// baseline (1456.570 us; speedup 1.0000x reference)
//
#include <hip/hip_runtime.h>
#include <math.h>

#define NT 4096
#define DM 1152
#define NH 16
#define DH 72
#define KRET 1638
#define NPR (NT - KRET)
#define CSB 8
#define CHUNK 205
#define SCALE 0.11785113019775793f
#define RSPLIT 2048.0f
#define INV_RSPLIT 4.8828125e-4f

typedef __attribute__((ext_vector_type(8))) short bf16x8;
typedef _Float16 f16;
typedef __attribute__((ext_vector_type(8))) _Float16 f16x8;
typedef __attribute__((ext_vector_type(4))) float f32x4;
typedef unsigned short ushort_t;

#define MFMA16(a, b, c) __builtin_amdgcn_mfma_f32_16x16x32_f16(a, b, c, 0, 0, 0)
#define MFMABF(a, b, c) __builtin_amdgcn_mfma_f32_16x16x32_bf16(a, b, c, 0, 0, 0)

__device__ inline ushort_t f2b(float f) {
    union { float f; unsigned int u; } v; v.f = f;
    unsigned int u = v.u;
    return (ushort_t)((u + 0x7FFFu + ((u >> 16) & 1u)) >> 16);
}

__device__ inline float b2f(ushort_t u) {
    union { unsigned int u; float f; } v; v.u = ((unsigned int)u) << 16;
    return v.f;
}

// tiled Q/K address: [NH][rowblk 256][ks 3][r 16][ki 32]
__device__ inline size_t qkAddr(int h, int row, int ks, int ki) {
    return ((((size_t)h * 256 + (row >> 4)) * 3 + ks) * 16 + (row & 15)) * 32 + ki;
}

// ---------- split x into fp16 hi/lo(x2048) planes + bf16 copy ----------------
__global__ __launch_bounds__(256) void split_x(
    const float* __restrict__ in, f16* __restrict__ x0, f16* __restrict__ x1,
    ushort_t* __restrict__ xb, int nElem)
{
    int i = blockIdx.x * 256 + threadIdx.x;
    int stride = gridDim.x * 256;
    for (; i < nElem; i += stride) {
        float v = in[i];
        f16 h0 = (f16)v;
        float res = (v - (float)h0) * RSPLIT;
        x0[i] = h0;
        x1[i] = (f16)res;
        xb[i] = f2b(v);
    }
}

__global__ __launch_bounds__(256) void transposeW_split(
    const float* __restrict__ W, f16* __restrict__ T0, f16* __restrict__ T1, int n)
{
    __shared__ float t[32][33];
    int bx = blockIdx.x * 32, by = blockIdx.y * 32;
    int tx = threadIdx.x & 31, ty = threadIdx.x >> 5;
    for (int i = ty; i < 32; i += 8)
        t[i][tx] = W[(size_t)(by + i) * n + bx + tx];
    __syncthreads();
    for (int i = ty; i < 32; i += 8) {
        float v = t[tx][i];
        f16 h0 = (f16)v;
        float res = (v - (float)h0) * RSPLIT;
        T0[(size_t)(bx + i) * n + by + tx] = h0;
        T1[(size_t)(bx + i) * n + by + tx] = (f16)res;
    }
}

__global__ __launch_bounds__(256) void transposeW_bf16(
    const float* __restrict__ W, ushort_t* __restrict__ WT, int n)
{
    __shared__ ushort_t t[32][33];
    int bx = blockIdx.x * 32, by = blockIdx.y * 32;
    int tx = threadIdx.x & 31, ty = threadIdx.x >> 5;
    for (int i = ty; i < 32; i += 8)
        t[i][tx] = f2b(W[(size_t)(by + i) * n + bx + tx]);
    __syncthreads();
    for (int i = ty; i < 32; i += 8)
        WT[(size_t)(bx + i) * n + by + tx] = t[tx][i];
}

// ---------- LDS-tiled split projection -> MFMA-tiled per-head output ---------
__global__ __launch_bounds__(256) void proj_split3(
    const f16* __restrict__ A0, const f16* __restrict__ A1,
    const f16* __restrict__ B0, const f16* __restrict__ B1,
    f16* __restrict__ Qt0, f16* __restrict__ Qt1)
{
    __shared__ __align__(16) f16 As0[128][40];
    __shared__ __align__(16) f16 As1[128][40];
    __shared__ __align__(16) f16 Bs0[64][40];
    __shared__ __align__(16) f16 Bs1[64][40];
    const int tid = threadIdx.x;
    const int wave = tid >> 6, lane = tid & 63;
    const int r = lane & 15, g = lane >> 4;
    const int row0 = blockIdx.y * 128;
    const int col0 = blockIdx.x * 64;
    f32x4 accM[2][4] = {}, accC[2][4] = {};
    for (int k0 = 0; k0 < DM; k0 += 32) {
        for (int idx = tid; idx < 128 * 4; idx += 256) {
            int row = idx >> 2, c = idx & 3;
            size_t src = (size_t)(row0 + row) * DM + k0 + c * 8;
            *(f16x8*)&As0[row][c * 8] = *(const f16x8*)(A0 + src);
            *(f16x8*)&As1[row][c * 8] = *(const f16x8*)(A1 + src);
        }
        for (int idx = tid; idx < 64 * 4; idx += 256) {
            int row = idx >> 2, c = idx & 3;
            size_t src = (size_t)(col0 + row) * DM + k0 + c * 8;
            *(f16x8*)&Bs0[row][c * 8] = *(const f16x8*)(B0 + src);
            *(f16x8*)&Bs1[row][c * 8] = *(const f16x8*)(B1 + src);
        }
        __syncthreads();
        f16x8 a0[2], a1[2], b0[4], b1[4];
#pragma unroll
        for (int rf = 0; rf < 2; ++rf) {
            a0[rf] = *(const f16x8*)&As0[wave * 32 + rf * 16 + r][g * 8];
            a1[rf] = *(const f16x8*)&As1[wave * 32 + rf * 16 + r][g * 8];
        }
#pragma unroll
        for (int cf = 0; cf < 4; ++cf) {
            b0[cf] = *(const f16x8*)&Bs0[cf * 16 + r][g * 8];
            b1[cf] = *(const f16x8*)&Bs1[cf * 16 + r][g * 8];
        }
#pragma unroll
        for (int rf = 0; rf < 2; ++rf)
#pragma unroll
            for (int cf = 0; cf < 4; ++cf) {
                accM[rf][cf] = MFMA16(a0[rf], b0[cf], accM[rf][cf]);
                accC[rf][cf] = MFMA16(a0[rf], b1[cf], accC[rf][cf]);
                accC[rf][cf] = MFMA16(a1[rf], b0[cf], accC[rf][cf]);
            }
        __syncthreads();
    }
#pragma unroll
    for (int rf = 0; rf < 2; ++rf)
#pragma unroll
        for (int cf = 0; cf < 4; ++cf) {
            int col = col0 + cf * 16 + r;
            int head = col / DH;
            int c = col - head * DH;
            int ks = c >> 5, ki = c & 31;
#pragma unroll
            for (int j = 0; j < 4; ++j) {
                int row = row0 + wave * 32 + rf * 16 + g * 4 + j;
                float v = accM[rf][cf][j] + accC[rf][cf][j] * INV_RSPLIT;
                f16 h0 = (f16)v;
                float res = (v - (float)h0) * RSPLIT;
                size_t addr = qkAddr(head, row, ks, ki);
                Qt0[addr] = h0;
                Qt1[addr] = (f16)res;
            }
        }
}

// ---------- LDS-tiled bf16 MFMA GEMM; mode 0 = fp32 flat, 2 = Vp tiled -------
__global__ __launch_bounds__(256) void gemm_bf16_lds(
    const ushort_t* __restrict__ A, const ushort_t* __restrict__ BT,
    const float* __restrict__ bias, void* __restrict__ C, int mode,
    int Nn, int K)
{
    __shared__ __align__(16) ushort_t As[128][40];
    __shared__ __align__(16) ushort_t Bs[64][40];
    const int tid = threadIdx.x;
    const int wave = tid >> 6, lane = tid & 63;
    const int r = lane & 15, g = lane >> 4;
    const int row0 = blockIdx.y * 128;
    const int col0 = blockIdx.x * 64;
    f32x4 acc[2][4] = {};
    for (int k0 = 0; k0 < K; k0 += 32) {
        for (int idx = tid; idx < 128 * 4; idx += 256) {
            int row = idx >> 2, c = idx & 3;
            *(bf16x8*)&As[row][c * 8] = *(const bf16x8*)(A + (size_t)(row0 + row) * K + k0 + c * 8);
        }
        for (int idx = tid; idx < 64 * 4; idx += 256) {
            int row = idx >> 2, c = idx & 3;
            *(bf16x8*)&Bs[row][c * 8] = *(const bf16x8*)(BT + (size_t)(col0 + row) * K + k0 + c * 8);
        }
        __syncthreads();
        bf16x8 a[2], b[4];
#pragma unroll
        for (int rf = 0; rf < 2; ++rf)
            a[rf] = *(const bf16x8*)&As[wave * 32 + rf * 16 + r][g * 8];
#pragma unroll
        for (int cf = 0; cf < 4; ++cf)
            b[cf] = *(const bf16x8*)&Bs[cf * 16 + r][g * 8];
#pragma unroll
        for (int rf = 0; rf < 2; ++rf)
#pragma unroll
            for (int cf = 0; cf < 4; ++cf)
                acc[rf][cf] = MFMABF(a[rf], b[cf], acc[rf][cf]);
        __syncthreads();
    }
#pragma unroll
    for (int rf = 0; rf < 2; ++rf)
#pragma unroll
        for (int cf = 0; cf < 4; ++cf) {
            int col = col0 + cf * 16 + r;
            float bv = bias ? bias[col] : 0.f;
#pragma unroll
            for (int j = 0; j < 4; ++j) {
                int row = row0 + wave * 32 + rf * 16 + g * 4 + j;
                float vv = acc[rf][cf][j] + bv;
                if (mode == 2) {
                    int head = col / DH;
                    int d = col - head * DH;
                    size_t addr = (((size_t)head * 128 + (row >> 5)) * 80 + d) * 32 + (row & 31);
                    ((ushort_t*)C)[addr] = f2b(vv);
                } else {
                    ((float*)C)[(size_t)row * Nn + col] = vv;
                }
            }
        }
}

// ---------- pass A: per-row 1/rowsum of exp(S); K staged in LDS (padded) -----
// grid (NT/64, NH), 256 threads. Tile rows padded 32->40 f16 (bank-conflict-free).
__global__ __launch_bounds__(256) void rowsum4(
    const f16* __restrict__ Qt0, const f16* __restrict__ Qt1,
    const f16* __restrict__ Kt0, const f16* __restrict__ Kt1,
    float* __restrict__ invs)
{
    __shared__ __align__(16) f16 KL[2][7680];   // [plane][12 tiles of 16x40]
    const int tid = threadIdx.x;
    const int wv = tid >> 6, lane = tid & 63;
    const int r = lane & 15, g = lane >> 4;
    const int h = blockIdx.y;
    const int rowblk = blockIdx.x * 4 + wv;
    f16x8 a0[3], a1[3];
#pragma unroll
    for (int ks = 0; ks < 3; ++ks) {
        size_t o = ((((size_t)h * 256 + rowblk) * 3 + ks) * 16) * 32 + r * 32 + g * 8;
        a0[ks] = *(const f16x8*)(Qt0 + o);
        a1[ks] = *(const f16x8*)(Qt1 + o);
    }
    const int srow = lane >> 2, spos = lane & 3;   // stage mapping within a tile
    float rs0 = 0.f, rs1 = 0.f, rs2 = 0.f, rs3 = 0.f;
    for (int ct = 0; ct < 64; ++ct) {
        __syncthreads();
        const size_t ctBase = ((size_t)h * 256 + ct * 4) * 1536;
#pragma unroll
        for (int s = 0; s < 6; ++s) {
            int wc = s * 4 + wv;             // 0..23 wave-chunks (one tile each)
            int plane = wc >= 12;
            int cip = wc - plane * 12;       // tile index within plane
            const f16* src = (plane ? Kt1 : Kt0) + ctBase + cip * 512 + lane * 8;
            *(f16x8*)&KL[plane][cip * 640 + srow * 40 + spos * 8] = *(const f16x8*)src;
        }
        __syncthreads();
        f32x4 accM[4] = {}, accC[4] = {};
#pragma unroll
        for (int ks = 0; ks < 3; ++ks) {
#pragma unroll
            for (int cf = 0; cf < 4; ++cf) {
                f16x8 b0 = *(const f16x8*)&KL[0][(cf * 3 + ks) * 640 + r * 40 + g * 8];
                f16x8 b1 = *(const f16x8*)&KL[1][(cf * 3 + ks) * 640 + r * 40 + g * 8];
                accM[cf] = MFMA16(a0[ks], b0, accM[cf]);
                accC[cf] = MFMA16(a0[ks], b1, accC[cf]);
                accC[cf] = MFMA16(a1[ks], b0, accC[cf]);
            }
        }
#pragma unroll
        for (int cf = 0; cf < 4; ++cf) {
            rs0 += __expf((accM[cf][0] + accC[cf][0] * INV_RSPLIT) * SCALE);
            rs1 += __expf((accM[cf][1] + accC[cf][1] * INV_RSPLIT) * SCALE);
            rs2 += __expf((accM[cf][2] + accC[cf][2] * INV_RSPLIT) * SCALE);
            rs3 += __expf((accM[cf][3] + accC[cf][3] * INV_RSPLIT) * SCALE);
        }
    }
#pragma unroll
    for (int m = 1; m <= 8; m <<= 1) {
        rs0 += __shfl_xor(rs0, m);
        rs1 += __shfl_xor(rs1, m);
        rs2 += __shfl_xor(rs2, m);
        rs3 += __shfl_xor(rs3, m);
    }
    if (r == 0) {
        int rbase = rowblk * 16 + g * 4;
        invs[(size_t)h * NT + rbase + 0] = 1.0f / rs0;
        invs[(size_t)h * NT + rbase + 1] = 1.0f / rs1;
        invs[(size_t)h * NT + rbase + 2] = 1.0f / rs2;
        invs[(size_t)h * NT + rbase + 3] = 1.0f / rs3;
    }
}

// ---------- pass B: fused QK^T->P->attn(+pair)->PV; K staged in LDS (padded) -
__global__ __launch_bounds__(256) void fused4(
    const f16* __restrict__ Qt0, const f16* __restrict__ Qt1,
    const f16* __restrict__ Kt0, const f16* __restrict__ Kt1,
    const float* __restrict__ invs, const ushort_t* __restrict__ Vp,
    float* __restrict__ attn, ushort_t* __restrict__ part_pv,
    int hpair, int first)
{
    __shared__ __align__(16) f16 KL[4][7680];   // [hh*2+plane][12 tiles of 16x40]
    __shared__ ushort_t Pt[64][88];
    const int tid = threadIdx.x;
    const int wr = tid >> 6, lane = tid & 63;
    const int r = lane & 15, g = lane >> 4;
    const int cs = blockIdx.x;
    const int rowblk = blockIdx.y * 4 + wr;
    const int row0 = rowblk * 16;
    f16x8 a0[2][3], a1[2][3];
    float vinv[2][4];
    f32x4 oacc[2][5] = {};
#pragma unroll
    for (int hh = 0; hh < 2; ++hh) {
        int h = hpair * 2 + hh;
#pragma unroll
        for (int ks = 0; ks < 3; ++ks) {
            size_t o = ((((size_t)h * 256 + rowblk) * 3 + ks) * 16) * 32 + r * 32 + g * 8;
            a0[hh][ks] = *(const f16x8*)(Qt0 + o);
            a1[hh][ks] = *(const f16x8*)(Qt1 + o);
        }
#pragma unroll
        for (int j = 0; j < 4; ++j)
            vinv[hh][j] = invs[(size_t)h * NT + row0 + g * 4 + j];
    }
    const int srow = lane >> 2, spos = lane & 3;
    for (int ct = 0; ct < 8; ++ct) {
        const int colbase = cs * 512 + ct * 64;
        const int cb0 = colbase >> 4;           // colblk base
        __syncthreads();
#pragma unroll
        for (int s = 0; s < 12; ++s) {
            int wc = s * 4 + wr;                // 0..47 wave-chunks (one tile each)
            int seg = wc / 12;                  // hh*2 + plane
            int cip = wc - seg * 12;
            int hh = seg >> 1, pl = seg & 1;
            const f16* base = pl ? Kt1 : Kt0;
            size_t srcOff = (((size_t)(hpair * 2 + hh) * 256 + cb0)) * 1536 + cip * 512 + lane * 8;
            *(f16x8*)&KL[seg][cip * 640 + srow * 40 + spos * 8] = *(const f16x8*)(base + srcOff);
        }
        __syncthreads();
        float P0[4][4];
#pragma unroll
        for (int hh = 0; hh < 2; ++hh) {
            const int h = hpair * 2 + hh;
            f32x4 accM[4] = {}, accC[4] = {};
#pragma unroll
            for (int ks = 0; ks < 3; ++ks) {
#pragma unroll
                for (int cf = 0; cf < 4; ++cf) {
                    f16x8 b0 = *(const f16x8*)&KL[hh * 2 + 0][(cf * 3 + ks) * 640 + r * 40 + g * 8];
                    f16x8 b1 = *(const f16x8*)&KL[hh * 2 + 1][(cf * 3 + ks) * 640 + r * 40 + g * 8];
                    accM[cf] = MFMA16(a0[hh][ks], b0, accM[cf]);
                    accC[cf] = MFMA16(a0[hh][ks], b1, accC[cf]);
                    accC[cf] = MFMA16(a1[hh][ks], b0, accC[cf]);
                }
            }
#pragma unroll
            for (int cf = 0; cf < 4; ++cf) {
#pragma unroll
                for (int j = 0; j < 4; ++j) {
                    float s = (accM[cf][j] + accC[cf][j] * INV_RSPLIT) * SCALE;
                    float p = __expf(s) * vinv[hh][j];
                    Pt[wr * 16 + g * 4 + j][cf * 16 + r] = f2b(p);
                    if (hh == 0) {
                        P0[cf][j] = p;
                    } else {
                        int row = row0 + g * 4 + j;
                        size_t aoff = (size_t)row * NT + colbase + cf * 16 + r;
                        float av = (P0[cf][j] + p) * 0.0625f;
                        if (first) attn[aoff] = av;
                        else       attn[aoff] += av;
                    }
                }
            }
            const int kt0 = colbase >> 5;
#pragma unroll
            for (int ks2 = 0; ks2 < 2; ++ks2) {
                bf16x8 pa = *(const bf16x8*)&Pt[wr * 16 + r][ks2 * 32 + g * 8];
#pragma unroll
                for (int t = 0; t < 5; ++t) {
                    int col = t * 16 + r;
                    size_t vo = (((size_t)h * 128 + kt0 + ks2) * 80 + col) * 32 + g * 8;
                    bf16x8 b = *(const bf16x8*)(Vp + vo);
                    oacc[hh][t] = MFMABF(pa, b, oacc[hh][t]);
                }
            }
        }
    }
#pragma unroll
    for (int hh = 0; hh < 2; ++hh)
#pragma unroll
        for (int t = 0; t < 5; ++t) {
            int col = t * 16 + r;
            if (col < DH) {
#pragma unroll
                for (int j = 0; j < 4; ++j) {
                    int row = row0 + g * 4 + j;
                    part_pv[(((size_t)cs * 2 + hh) * NT + row) * DH + col] = f2b(oacc[hh][t][j]);
                }
            }
        }
}

__global__ __launch_bounds__(256) void pv_reduce2h(
    const ushort_t* __restrict__ part_pv, ushort_t* __restrict__ otmpb, int hpair)
{
    int idx = blockIdx.x * 256 + threadIdx.x;
    if (idx >= 2 * NT * DH) return;
    int hh = idx / (NT * DH);
    int rem = idx - hh * NT * DH;
    int row = rem / DH, col = rem - row * DH;
    float s = 0.f;
#pragma unroll
    for (int cs = 0; cs < CSB; ++cs)
        s += b2f(part_pv[(((size_t)cs * 2 + hh) * NT + row) * DH + col]);
    otmpb[(size_t)row * DM + (hpair * 2 + hh) * DH + col] = f2b(s);
}

// ---------- pagerank power iteration (fp32, unchanged) -----------------------
__global__ __launch_bounds__(256) void init_dist(float* __restrict__ d)
{
    int t = blockIdx.x * 256 + threadIdx.x;
    if (t < NT) d[t] = 1.0f / NT;
}

__global__ __launch_bounds__(256) void power_a(
    const float* __restrict__ attn, const float* __restrict__ din,
    float* __restrict__ part)
{
    int j = blockIdx.x * 256 + threadIdx.x;
    int i0 = blockIdx.y * 128;
    float acc = 0.f;
    for (int i = i0; i < i0 + 128; ++i)
        acc += din[i] * attn[(size_t)i * NT + j];
    part[(size_t)blockIdx.y * NT + j] = acc;
}

__global__ __launch_bounds__(256) void power_b(
    const float* __restrict__ part, float* __restrict__ dout)
{
    int j = blockIdx.x * 256 + threadIdx.x;
    float acc = 0.f;
    for (int ib = 0; ib < 32; ++ib) acc += part[(size_t)ib * NT + j];
    dout[j] = acc;
}

// ---------- top-k: tiled rank counting (deterministic int atomics) -----------
__global__ __launch_bounds__(256) void rank_count(
    const float* __restrict__ imp, int* __restrict__ rank, int* __restrict__ prank)
{
    __shared__ float sj[256];
    const int tid = threadIdx.x;
    const int jb = blockIdx.y * 256;
    sj[tid] = imp[jb + tid];
    __syncthreads();
    const int i = blockIdx.x * 256 + tid;
    const float mv = imp[i];
    int r = 0, rp = 0;
    for (int jj = 0; jj < 256; ++jj) {
        float vj = sj[jj];
        int j = jb + jj;
        int tie_low = (vj == mv) && (j < i);
        r  += (vj > mv) || tie_low;
        rp += (vj < mv) || tie_low;
    }
    atomicAdd(&rank[i], r);
    atomicAdd(&prank[i], rp);
}

__global__ __launch_bounds__(256) void scatter_topk2(
    const int* __restrict__ rank, const int* __restrict__ prank,
    float* __restrict__ out_imps, float* __restrict__ out_prune,
    int* __restrict__ imp_rows, int* __restrict__ prune_cols)
{
    __shared__ unsigned char fr[NT];
    __shared__ unsigned char fp[NT];
    __shared__ int sr[256], sp[256];
    const int tid = threadIdx.x;
    for (int t = tid; t < NT; t += 256) {
        fr[t] = rank[t] < KRET;
        fp[t] = prank[t] < NPR;
    }
    __syncthreads();
    const int base = tid * 16;
    int cr = 0, cp = 0;
#pragma unroll
    for (int e = 0; e < 16; ++e) { cr += fr[base + e]; cp += fp[base + e]; }
    sr[tid] = cr; sp[tid] = cp;
    __syncthreads();
    int pr = 0, pp = 0;
    for (int j = 0; j < tid; ++j) { pr += sr[j]; pp += sp[j]; }
#pragma unroll
    for (int e = 0; e < 16; ++e) {
        int i = base + e;
        if (fr[i]) { out_imps[pr] = (float)i; imp_rows[pr] = i; ++pr; }
        if (fp[i]) { out_prune[pp] = (float)i; prune_cols[pp] = i; ++pp; }
    }
}

__global__ __launch_bounds__(256) void argmax_part(
    const float* __restrict__ attn, const int* __restrict__ imp_rows,
    float* __restrict__ pbest, int* __restrict__ pbi)
{
    __shared__ int rows[CHUNK];
    const int tid = threadIdx.x;
    const int rc = blockIdx.y;
    const int r0 = rc * CHUNK;
    const int nr = min(KRET - r0, CHUNK);
    for (int t = tid; t < nr; t += 256) rows[t] = imp_rows[r0 + t];
    __syncthreads();
    const int j = blockIdx.x * 256 + tid;
    float best = -INFINITY;
    int bi = 0;
    for (int rr = 0; rr < nr; ++rr) {
        float val = attn[(size_t)rows[rr] * NT + j];
        if (val > best) { best = val; bi = r0 + rr; }
    }
    pbest[(size_t)rc * NT + j] = best;
    pbi[(size_t)rc * NT + j] = bi;
}

__global__ __launch_bounds__(256) void argmax_red(
    const float* __restrict__ pbest, const int* __restrict__ pbi,
    int* __restrict__ maxind)
{
    const int j = blockIdx.x * 256 + threadIdx.x;
    float best = -INFINITY;
    int bi = 0;
#pragma unroll
    for (int rc = 0; rc < 8; ++rc) {
        float val = pbest[(size_t)rc * NT + j];
        if (val > best) { best = val; bi = pbi[(size_t)rc * NT + j]; }
    }
    maxind[j] = bi;
}

__global__ __launch_bounds__(256) void finalize(
    const float* __restrict__ dist, const int* __restrict__ prune_cols,
    const int* __restrict__ maxind, float* __restrict__ out_imp,
    float* __restrict__ out_simi)
{
    int t = blockIdx.x * 256 + threadIdx.x;
    if (t < NT) out_imp[t] = dist[t];
    if (t < NPR) out_simi[t] = (float)maxind[prune_cols[t]];
}

extern "C" void kernel_launch(void* const* d_in, const int* in_sizes, int n_in,
                              void* d_out, int out_size, void* d_ws, size_t ws_size,
                              hipStream_t stream)
{
    const float* x  = (const float*)d_in[0];
    const float* Wq = (const float*)d_in[1];
    const float* Wk = (const float*)d_in[2];
    const float* Wv = (const float*)d_in[3];
    const float* Wo = (const float*)d_in[4];
    const float* bo = (const float*)d_in[5];
    float* out = (float*)d_out;

    const size_t QKT_EL = (size_t)NH * 256 * 3 * 16 * 32;   // 6.29M f16 per plane
    const size_t VP_EL  = (size_t)NH * 128 * 80 * 32;       // 5.24M bf16

    // ---- workspace layout (float units) ----
    float* ws = (float*)d_ws;
    size_t off = 0;
    float* attn = ws + off; off += (size_t)NT * NT;
    f16* Qt0 = (f16*)(ws + off); off += QKT_EL / 2;
    f16* Qt1 = (f16*)(ws + off); off += QKT_EL / 2;
    f16* Kt0 = (f16*)(ws + off); off += QKT_EL / 2;
    f16* Kt1 = (f16*)(ws + off); off += QKT_EL / 2;
    ushort_t* Vp = (ushort_t*)(ws + off); off += VP_EL / 2;
    size_t zero_floats = 4 * (QKT_EL / 2) + VP_EL / 2;      // Qt0..Vp contiguous
    ushort_t* otmpb = (ushort_t*)(ws + off); off += ((size_t)NT * DM) / 2;
    f16* X0 = (f16*)(ws + off); f16* X1 = X0 + (size_t)NT * DM; off += (size_t)NT * DM;
    f16* T0 = (f16*)(ws + off); f16* T1 = T0 + (size_t)DM * DM; off += (size_t)DM * DM;
    ushort_t* Wslot = (ushort_t*)(ws + off); off += ((size_t)DM * DM) / 2;
    float* invs    = ws + off; off += (size_t)NH * NT;
    ushort_t* part_pv = (ushort_t*)(ws + off); off += (size_t)CSB * 2 * NT * DH / 2;
    float* pbest   = ws + off; off += 8 * NT;
    int*   pbi     = (int*)(ws + off); off += 8 * NT;
    float* dist0 = ws + off; off += NT;
    float* dist1 = ws + off; off += NT;
    float* partial = ws + off; off += 32 * NT;
    int* rank      = (int*)(ws + off); off += NT;
    int* prank     = (int*)(ws + off); off += NT;
    int* imp_rows  = (int*)(ws + off); off += 2048;
    int* prune_cols= (int*)(ws + off); off += 2560;
    int* maxind    = (int*)(ws + off); off += NT;

    // setup-only alias inside attn region (dead before fused4 pair0 writes)
    ushort_t* xb = (ushort_t*)attn;

    // output layout
    float* out_out   = out;
    float* out_imp   = out + (size_t)NT * DM;
    float* out_imps  = out_imp + NT;
    float* out_prune = out_imps + KRET;
    float* out_simi  = out_prune + NPR;

    // ---- setup ----
    hipMemsetAsync(Qt0, 0, zero_floats * sizeof(float), stream);  // zero-pad tiles
    split_x<<<2048, 256, 0, stream>>>(x, X0, X1, xb, NT * DM);

    dim3 gT(DM / 32, DM / 32);
    dim3 gP(DM / 64, NT / 128);
    transposeW_split<<<gT, 256, 0, stream>>>(Wq, T0, T1, DM);
    proj_split3<<<gP, 256, 0, stream>>>(X0, X1, T0, T1, Qt0, Qt1);
    transposeW_split<<<gT, 256, 0, stream>>>(Wk, T0, T1, DM);
    proj_split3<<<gP, 256, 0, stream>>>(X0, X1, T0, T1, Kt0, Kt1);

    transposeW_bf16<<<gT, 256, 0, stream>>>(Wv, Wslot, DM);
    gemm_bf16_lds<<<gP, 256, 0, stream>>>(xb, Wslot, nullptr, Vp, 2, DM, DM);

    // ---- pass A: inverse row sums (LDS-staged K, padded) ----
    rowsum4<<<dim3(NT / 64, NH), 256, 0, stream>>>(Qt0, Qt1, Kt0, Kt1, invs);

    // ---- pass B: fused attention, 2 heads per launch (LDS-staged K, padded) --
    for (int hp = 0; hp < NH / 2; ++hp) {
        fused4<<<dim3(CSB, NT / 64), 256, 0, stream>>>(
            Qt0, Qt1, Kt0, Kt1, invs, Vp, attn, part_pv, hp, hp == 0 ? 1 : 0);
        pv_reduce2h<<<(2 * NT * DH + 255) / 256, 256, 0, stream>>>(part_pv, otmpb, hp);
    }

    // ---- output projection ----
    transposeW_bf16<<<gT, 256, 0, stream>>>(Wo, Wslot, DM);
    gemm_bf16_lds<<<gP, 256, 0, stream>>>(otmpb, Wslot, bo, out_out, 0, DM, DM);

    // ---- pagerank ----
    init_dist<<<16, 256, 0, stream>>>(dist0);
    float* da = dist0;
    float* db = dist1;
    for (int it = 0; it < 5; ++it) {
        power_a<<<dim3(16, 32), 256, 0, stream>>>(attn, da, partial);
        power_b<<<16, 256, 0, stream>>>(partial, db);
        float* t = da; da = db; db = t;
    }

    // ---- top-k ----
    hipMemsetAsync(rank, 0, 2 * NT * sizeof(int), stream);
    rank_count<<<dim3(16, 16), 256, 0, stream>>>(da, rank, prank);
    scatter_topk2<<<1, 256, 0, stream>>>(rank, prank, out_imps, out_prune,
                                         imp_rows, prune_cols);
    argmax_part<<<dim3(16, 8), 256, 0, stream>>>(attn, imp_rows, pbest, pbi);
    argmax_red<<<16, 256, 0, stream>>>(pbest, pbi, maxind);
    finalize<<<16, 256, 0, stream>>>(da, prune_cols, maxind, out_imp, out_simi);
}

// Round 9
// 1445.040 us; speedup vs baseline: 1.0080x; 1.0080x over previous
//
#include <hip/hip_runtime.h>
#include <math.h>

#define NT 4096
#define DM 1152
#define NH 16
#define DH 72
#define KRET 1638
#define NPR (NT - KRET)
#define CSB 8
#define CHUNK 205
#define SCALE 0.11785113019775793f
#define RSPLIT 2048.0f
#define INV_RSPLIT 4.8828125e-4f

typedef __attribute__((ext_vector_type(8))) short bf16x8;
typedef _Float16 f16;
typedef __attribute__((ext_vector_type(8))) _Float16 f16x8;
typedef __attribute__((ext_vector_type(4))) float f32x4;
typedef unsigned short ushort_t;

#define MFMA16(a, b, c) __builtin_amdgcn_mfma_f32_16x16x32_f16(a, b, c, 0, 0, 0)
#define MFMABF(a, b, c) __builtin_amdgcn_mfma_f32_16x16x32_bf16(a, b, c, 0, 0, 0)

__device__ inline ushort_t f2b(float f) {
    union { float f; unsigned int u; } v; v.f = f;
    unsigned int u = v.u;
    return (ushort_t)((u + 0x7FFFu + ((u >> 16) & 1u)) >> 16);
}

__device__ inline float b2f(ushort_t u) {
    union { unsigned int u; float f; } v; v.u = ((unsigned int)u) << 16;
    return v.f;
}

// tiled Q/K address: [NH][rowblk 256][ks 3][r 16][ki 32]
__device__ inline size_t qkAddr(int h, int row, int ks, int ki) {
    return ((((size_t)h * 256 + (row >> 4)) * 3 + ks) * 16 + (row & 15)) * 32 + ki;
}

// ---------- split x into fp16 hi/lo(x2048) planes + bf16 copy ----------------
__global__ __launch_bounds__(256) void split_x(
    const float* __restrict__ in, f16* __restrict__ x0, f16* __restrict__ x1,
    ushort_t* __restrict__ xb, int nElem)
{
    int i = blockIdx.x * 256 + threadIdx.x;
    int stride = gridDim.x * 256;
    for (; i < nElem; i += stride) {
        float v = in[i];
        f16 h0 = (f16)v;
        float res = (v - (float)h0) * RSPLIT;
        x0[i] = h0;
        x1[i] = (f16)res;
        xb[i] = f2b(v);
    }
}

__global__ __launch_bounds__(256) void transposeW_split(
    const float* __restrict__ W, f16* __restrict__ T0, f16* __restrict__ T1, int n)
{
    __shared__ float t[32][33];
    int bx = blockIdx.x * 32, by = blockIdx.y * 32;
    int tx = threadIdx.x & 31, ty = threadIdx.x >> 5;
    for (int i = ty; i < 32; i += 8)
        t[i][tx] = W[(size_t)(by + i) * n + bx + tx];
    __syncthreads();
    for (int i = ty; i < 32; i += 8) {
        float v = t[tx][i];
        f16 h0 = (f16)v;
        float res = (v - (float)h0) * RSPLIT;
        T0[(size_t)(bx + i) * n + by + tx] = h0;
        T1[(size_t)(bx + i) * n + by + tx] = (f16)res;
    }
}

__global__ __launch_bounds__(256) void transposeW_bf16(
    const float* __restrict__ W, ushort_t* __restrict__ WT, int n)
{
    __shared__ ushort_t t[32][33];
    int bx = blockIdx.x * 32, by = blockIdx.y * 32;
    int tx = threadIdx.x & 31, ty = threadIdx.x >> 5;
    for (int i = ty; i < 32; i += 8)
        t[i][tx] = f2b(W[(size_t)(by + i) * n + bx + tx]);
    __syncthreads();
    for (int i = ty; i < 32; i += 8)
        WT[(size_t)(bx + i) * n + by + tx] = t[tx][i];
}

// ---------- LDS-tiled split projection -> MFMA-tiled per-head output ---------
// scl: output pre-scale (SCALE for Q, 1.0 for K) applied before re-splitting.
__global__ __launch_bounds__(256) void proj_split3(
    const f16* __restrict__ A0, const f16* __restrict__ A1,
    const f16* __restrict__ B0, const f16* __restrict__ B1,
    f16* __restrict__ Qt0, f16* __restrict__ Qt1, float scl)
{
    __shared__ __align__(16) f16 As0[128][40];
    __shared__ __align__(16) f16 As1[128][40];
    __shared__ __align__(16) f16 Bs0[64][40];
    __shared__ __align__(16) f16 Bs1[64][40];
    const int tid = threadIdx.x;
    const int wave = tid >> 6, lane = tid & 63;
    const int r = lane & 15, g = lane >> 4;
    const int row0 = blockIdx.y * 128;
    const int col0 = blockIdx.x * 64;
    f32x4 accM[2][4] = {}, accC[2][4] = {};
    for (int k0 = 0; k0 < DM; k0 += 32) {
        for (int idx = tid; idx < 128 * 4; idx += 256) {
            int row = idx >> 2, c = idx & 3;
            size_t src = (size_t)(row0 + row) * DM + k0 + c * 8;
            *(f16x8*)&As0[row][c * 8] = *(const f16x8*)(A0 + src);
            *(f16x8*)&As1[row][c * 8] = *(const f16x8*)(A1 + src);
        }
        for (int idx = tid; idx < 64 * 4; idx += 256) {
            int row = idx >> 2, c = idx & 3;
            size_t src = (size_t)(col0 + row) * DM + k0 + c * 8;
            *(f16x8*)&Bs0[row][c * 8] = *(const f16x8*)(B0 + src);
            *(f16x8*)&Bs1[row][c * 8] = *(const f16x8*)(B1 + src);
        }
        __syncthreads();
        f16x8 a0[2], a1[2], b0[4], b1[4];
#pragma unroll
        for (int rf = 0; rf < 2; ++rf) {
            a0[rf] = *(const f16x8*)&As0[wave * 32 + rf * 16 + r][g * 8];
            a1[rf] = *(const f16x8*)&As1[wave * 32 + rf * 16 + r][g * 8];
        }
#pragma unroll
        for (int cf = 0; cf < 4; ++cf) {
            b0[cf] = *(const f16x8*)&Bs0[cf * 16 + r][g * 8];
            b1[cf] = *(const f16x8*)&Bs1[cf * 16 + r][g * 8];
        }
#pragma unroll
        for (int rf = 0; rf < 2; ++rf)
#pragma unroll
            for (int cf = 0; cf < 4; ++cf) {
                accM[rf][cf] = MFMA16(a0[rf], b0[cf], accM[rf][cf]);
                accC[rf][cf] = MFMA16(a0[rf], b1[cf], accC[rf][cf]);
                accC[rf][cf] = MFMA16(a1[rf], b0[cf], accC[rf][cf]);
            }
        __syncthreads();
    }
#pragma unroll
    for (int rf = 0; rf < 2; ++rf)
#pragma unroll
        for (int cf = 0; cf < 4; ++cf) {
            int col = col0 + cf * 16 + r;
            int head = col / DH;
            int c = col - head * DH;
            int ks = c >> 5, ki = c & 31;
#pragma unroll
            for (int j = 0; j < 4; ++j) {
                int row = row0 + wave * 32 + rf * 16 + g * 4 + j;
                float v = (accM[rf][cf][j] + accC[rf][cf][j] * INV_RSPLIT) * scl;
                f16 h0 = (f16)v;
                float res = (v - (float)h0) * RSPLIT;
                size_t addr = qkAddr(head, row, ks, ki);
                Qt0[addr] = h0;
                Qt1[addr] = (f16)res;
            }
        }
}

// ---------- LDS-tiled bf16 MFMA GEMM; mode 0 = fp32 flat, 2 = Vp tiled -------
__global__ __launch_bounds__(256) void gemm_bf16_lds(
    const ushort_t* __restrict__ A, const ushort_t* __restrict__ BT,
    const float* __restrict__ bias, void* __restrict__ C, int mode,
    int Nn, int K)
{
    __shared__ __align__(16) ushort_t As[128][40];
    __shared__ __align__(16) ushort_t Bs[64][40];
    const int tid = threadIdx.x;
    const int wave = tid >> 6, lane = tid & 63;
    const int r = lane & 15, g = lane >> 4;
    const int row0 = blockIdx.y * 128;
    const int col0 = blockIdx.x * 64;
    f32x4 acc[2][4] = {};
    for (int k0 = 0; k0 < K; k0 += 32) {
        for (int idx = tid; idx < 128 * 4; idx += 256) {
            int row = idx >> 2, c = idx & 3;
            *(bf16x8*)&As[row][c * 8] = *(const bf16x8*)(A + (size_t)(row0 + row) * K + k0 + c * 8);
        }
        for (int idx = tid; idx < 64 * 4; idx += 256) {
            int row = idx >> 2, c = idx & 3;
            *(bf16x8*)&Bs[row][c * 8] = *(const bf16x8*)(BT + (size_t)(col0 + row) * K + k0 + c * 8);
        }
        __syncthreads();
        bf16x8 a[2], b[4];
#pragma unroll
        for (int rf = 0; rf < 2; ++rf)
            a[rf] = *(const bf16x8*)&As[wave * 32 + rf * 16 + r][g * 8];
#pragma unroll
        for (int cf = 0; cf < 4; ++cf)
            b[cf] = *(const bf16x8*)&Bs[cf * 16 + r][g * 8];
#pragma unroll
        for (int rf = 0; rf < 2; ++rf)
#pragma unroll
            for (int cf = 0; cf < 4; ++cf)
                acc[rf][cf] = MFMABF(a[rf], b[cf], acc[rf][cf]);
        __syncthreads();
    }
#pragma unroll
    for (int rf = 0; rf < 2; ++rf)
#pragma unroll
        for (int cf = 0; cf < 4; ++cf) {
            int col = col0 + cf * 16 + r;
            float bv = bias ? bias[col] : 0.f;
#pragma unroll
            for (int j = 0; j < 4; ++j) {
                int row = row0 + wave * 32 + rf * 16 + g * 4 + j;
                float vv = acc[rf][cf][j] + bv;
                if (mode == 2) {
                    int head = col / DH;
                    int d = col - head * DH;
                    size_t addr = (((size_t)head * 128 + (row >> 5)) * 80 + d) * 32 + (row & 31);
                    ((ushort_t*)C)[addr] = f2b(vv);
                } else {
                    ((float*)C)[(size_t)row * Nn + col] = vv;
                }
            }
        }
}

// ---------- pass A: per-row 1/rowsum of exp(S); K staged in LDS (dense) ------
__global__ __launch_bounds__(256) void rowsum4(
    const f16* __restrict__ Qt0, const f16* __restrict__ Qt1,
    const f16* __restrict__ Kt0, const f16* __restrict__ Kt1,
    float* __restrict__ invs)
{
    __shared__ __align__(16) f16 KL[2][6144];   // [plane][12 tiles of 512]
    const int tid = threadIdx.x;
    const int wv = tid >> 6, lane = tid & 63;
    const int r = lane & 15, g = lane >> 4;
    const int h = blockIdx.y;
    const int rowblk = blockIdx.x * 4 + wv;
    f16x8 a0[3], a1[3];
#pragma unroll
    for (int ks = 0; ks < 3; ++ks) {
        size_t o = ((((size_t)h * 256 + rowblk) * 3 + ks) * 16) * 32 + r * 32 + g * 8;
        a0[ks] = *(const f16x8*)(Qt0 + o);
        a1[ks] = *(const f16x8*)(Qt1 + o);
    }
    float rs0 = 0.f, rs1 = 0.f, rs2 = 0.f, rs3 = 0.f;
    for (int ct = 0; ct < 64; ++ct) {
        __syncthreads();
        const size_t ctBase = ((size_t)h * 256 + ct * 4) * 1536;
#pragma unroll
        for (int s = 0; s < 6; ++s) {
            int wc = s * 4 + wv;             // 0..23 wave-chunks of 1024B
            int plane = wc >= 12;
            int cip = wc - plane * 12;
            const f16* src = (plane ? Kt1 : Kt0) + ctBase + cip * 512 + lane * 8;
            *(f16x8*)&KL[plane][cip * 512 + lane * 8] = *(const f16x8*)src;
        }
        __syncthreads();
        f32x4 accM[4] = {}, accC[4] = {};
#pragma unroll
        for (int ks = 0; ks < 3; ++ks) {
#pragma unroll
            for (int cf = 0; cf < 4; ++cf) {
                f16x8 b0 = *(const f16x8*)&KL[0][(cf * 3 + ks) * 512 + r * 32 + g * 8];
                f16x8 b1 = *(const f16x8*)&KL[1][(cf * 3 + ks) * 512 + r * 32 + g * 8];
                accM[cf] = MFMA16(a0[ks], b0, accM[cf]);
                accC[cf] = MFMA16(a0[ks], b1, accC[cf]);
                accC[cf] = MFMA16(a1[ks], b0, accC[cf]);
            }
        }
#pragma unroll
        for (int cf = 0; cf < 4; ++cf) {
            rs0 += __expf(accM[cf][0] + accC[cf][0] * INV_RSPLIT);
            rs1 += __expf(accM[cf][1] + accC[cf][1] * INV_RSPLIT);
            rs2 += __expf(accM[cf][2] + accC[cf][2] * INV_RSPLIT);
            rs3 += __expf(accM[cf][3] + accC[cf][3] * INV_RSPLIT);
        }
    }
#pragma unroll
    for (int m = 1; m <= 8; m <<= 1) {
        rs0 += __shfl_xor(rs0, m);
        rs1 += __shfl_xor(rs1, m);
        rs2 += __shfl_xor(rs2, m);
        rs3 += __shfl_xor(rs3, m);
    }
    if (r == 0) {
        int rbase = rowblk * 16 + g * 4;
        invs[(size_t)h * NT + rbase + 0] = 1.0f / rs0;
        invs[(size_t)h * NT + rbase + 1] = 1.0f / rs1;
        invs[(size_t)h * NT + rbase + 2] = 1.0f / rs2;
        invs[(size_t)h * NT + rbase + 3] = 1.0f / rs3;
    }
}

// ---------- pass B: fused QK^T->P->attn->PV; 4 heads per launch --------------
// attn accumulated in registers across the 4 heads, touched once per launch.
__global__ __launch_bounds__(256, 1) void fused5(
    const f16* __restrict__ Qt0, const f16* __restrict__ Qt1,
    const f16* __restrict__ Kt0, const f16* __restrict__ Kt1,
    const float* __restrict__ invs, const ushort_t* __restrict__ Vp,
    float* __restrict__ attn, ushort_t* __restrict__ part_pv,
    int hquad, int first)
{
    __shared__ __align__(16) f16 KL[4][6144];   // [pairhead*2+plane][12 tiles]
    __shared__ ushort_t Pt[64][88];
    const int tid = threadIdx.x;
    const int wr = tid >> 6, lane = tid & 63;
    const int r = lane & 15, g = lane >> 4;
    const int cs = blockIdx.x;
    const int rowblk = blockIdx.y * 4 + wr;
    const int row0 = rowblk * 16;
    float vinv[4][4];
    f32x4 oacc[4][5] = {};
#pragma unroll
    for (int hh = 0; hh < 4; ++hh) {
        int h = hquad * 4 + hh;
#pragma unroll
        for (int j = 0; j < 4; ++j)
            vinv[hh][j] = invs[(size_t)h * NT + row0 + g * 4 + j];
    }
    for (int ct = 0; ct < 8; ++ct) {
        const int colbase = cs * 512 + ct * 64;
        const int cb0 = colbase >> 4;
        const int kt0 = colbase >> 5;
        float attn_acc[4][4] = {};
#pragma unroll
        for (int pr2 = 0; pr2 < 2; ++pr2) {
            __syncthreads();
#pragma unroll
            for (int s = 0; s < 12; ++s) {
                int wc = s * 4 + wr;            // 0..47 wave-chunks of 1024B
                int seg = wc / 12;              // hh-in-pair*2 + plane
                int cip = wc - seg * 12;
                int hh = seg >> 1, pl = seg & 1;
                const f16* base = pl ? Kt1 : Kt0;
                size_t srcOff = ((size_t)(hquad * 4 + pr2 * 2 + hh) * 256 + cb0) * 1536
                              + cip * 512 + lane * 8;
                *(f16x8*)&KL[seg][cip * 512 + lane * 8] = *(const f16x8*)(base + srcOff);
            }
            __syncthreads();
#pragma unroll
            for (int hh2 = 0; hh2 < 2; ++hh2) {
                const int hh = pr2 * 2 + hh2;
                const int h = hquad * 4 + hh;
                // Q fragments for this head (L2-resident tiled loads)
                f16x8 a0[3], a1[3];
#pragma unroll
                for (int ks = 0; ks < 3; ++ks) {
                    size_t o = ((((size_t)h * 256 + rowblk) * 3 + ks) * 16) * 32 + r * 32 + g * 8;
                    a0[ks] = *(const f16x8*)(Qt0 + o);
                    a1[ks] = *(const f16x8*)(Qt1 + o);
                }
                f32x4 accM[4] = {}, accC[4] = {};
#pragma unroll
                for (int ks = 0; ks < 3; ++ks) {
#pragma unroll
                    for (int cf = 0; cf < 4; ++cf) {
                        f16x8 b0 = *(const f16x8*)&KL[hh2 * 2 + 0][(cf * 3 + ks) * 512 + r * 32 + g * 8];
                        f16x8 b1 = *(const f16x8*)&KL[hh2 * 2 + 1][(cf * 3 + ks) * 512 + r * 32 + g * 8];
                        accM[cf] = MFMA16(a0[ks], b0, accM[cf]);
                        accC[cf] = MFMA16(a0[ks], b1, accC[cf]);
                        accC[cf] = MFMA16(a1[ks], b0, accC[cf]);
                    }
                }
#pragma unroll
                for (int cf = 0; cf < 4; ++cf) {
#pragma unroll
                    for (int j = 0; j < 4; ++j) {
                        float s = accM[cf][j] + accC[cf][j] * INV_RSPLIT;
                        float p = __expf(s) * vinv[hh][j];
                        Pt[wr * 16 + g * 4 + j][cf * 16 + r] = f2b(p);
                        attn_acc[cf][j] += p;
                    }
                }
                // PV (wave-private Pt rows; no barrier needed)
#pragma unroll
                for (int ks2 = 0; ks2 < 2; ++ks2) {
                    bf16x8 pa = *(const bf16x8*)&Pt[wr * 16 + r][ks2 * 32 + g * 8];
#pragma unroll
                    for (int t = 0; t < 5; ++t) {
                        int col = t * 16 + r;
                        size_t vo = (((size_t)h * 128 + kt0 + ks2) * 80 + col) * 32 + g * 8;
                        bf16x8 b = *(const bf16x8*)(Vp + vo);
                        oacc[hh][t] = MFMABF(pa, b, oacc[hh][t]);
                    }
                }
            }
        }
        // attn touched once per launch for this tile
#pragma unroll
        for (int cf = 0; cf < 4; ++cf) {
#pragma unroll
            for (int j = 0; j < 4; ++j) {
                int row = row0 + g * 4 + j;
                size_t aoff = (size_t)row * NT + colbase + cf * 16 + r;
                float av = attn_acc[cf][j] * 0.0625f;
                if (first) attn[aoff] = av;
                else       attn[aoff] += av;
            }
        }
    }
#pragma unroll
    for (int hh = 0; hh < 4; ++hh)
#pragma unroll
        for (int t = 0; t < 5; ++t) {
            int col = t * 16 + r;
            if (col < DH) {
#pragma unroll
                for (int j = 0; j < 4; ++j) {
                    int row = row0 + g * 4 + j;
                    part_pv[(((size_t)cs * 4 + hh) * NT + row) * DH + col] = f2b(oacc[hh][t][j]);
                }
            }
        }
}

__global__ __launch_bounds__(256) void pv_reduce4h(
    const ushort_t* __restrict__ part_pv, ushort_t* __restrict__ otmpb, int hquad)
{
    int idx = blockIdx.x * 256 + threadIdx.x;
    if (idx >= 4 * NT * DH) return;
    int hh = idx / (NT * DH);
    int rem = idx - hh * NT * DH;
    int row = rem / DH, col = rem - row * DH;
    float s = 0.f;
#pragma unroll
    for (int cs = 0; cs < CSB; ++cs)
        s += b2f(part_pv[(((size_t)cs * 4 + hh) * NT + row) * DH + col]);
    otmpb[(size_t)row * DM + (hquad * 4 + hh) * DH + col] = f2b(s);
}

// ---------- pagerank power iteration (fp32, unchanged) -----------------------
__global__ __launch_bounds__(256) void init_dist(float* __restrict__ d)
{
    int t = blockIdx.x * 256 + threadIdx.x;
    if (t < NT) d[t] = 1.0f / NT;
}

__global__ __launch_bounds__(256) void power_a(
    const float* __restrict__ attn, const float* __restrict__ din,
    float* __restrict__ part)
{
    int j = blockIdx.x * 256 + threadIdx.x;
    int i0 = blockIdx.y * 128;
    float acc = 0.f;
    for (int i = i0; i < i0 + 128; ++i)
        acc += din[i] * attn[(size_t)i * NT + j];
    part[(size_t)blockIdx.y * NT + j] = acc;
}

__global__ __launch_bounds__(256) void power_b(
    const float* __restrict__ part, float* __restrict__ dout)
{
    int j = blockIdx.x * 256 + threadIdx.x;
    float acc = 0.f;
    for (int ib = 0; ib < 32; ++ib) acc += part[(size_t)ib * NT + j];
    dout[j] = acc;
}

// ---------- top-k: tiled rank counting (deterministic int atomics) -----------
__global__ __launch_bounds__(256) void rank_count(
    const float* __restrict__ imp, int* __restrict__ rank, int* __restrict__ prank)
{
    __shared__ float sj[256];
    const int tid = threadIdx.x;
    const int jb = blockIdx.y * 256;
    sj[tid] = imp[jb + tid];
    __syncthreads();
    const int i = blockIdx.x * 256 + tid;
    const float mv = imp[i];
    int r = 0, rp = 0;
    for (int jj = 0; jj < 256; ++jj) {
        float vj = sj[jj];
        int j = jb + jj;
        int tie_low = (vj == mv) && (j < i);
        r  += (vj > mv) || tie_low;
        rp += (vj < mv) || tie_low;
    }
    atomicAdd(&rank[i], r);
    atomicAdd(&prank[i], rp);
}

__global__ __launch_bounds__(256) void scatter_topk2(
    const int* __restrict__ rank, const int* __restrict__ prank,
    float* __restrict__ out_imps, float* __restrict__ out_prune,
    int* __restrict__ imp_rows, int* __restrict__ prune_cols)
{
    __shared__ unsigned char fr[NT];
    __shared__ unsigned char fp[NT];
    __shared__ int sr[256], sp[256];
    const int tid = threadIdx.x;
    for (int t = tid; t < NT; t += 256) {
        fr[t] = rank[t] < KRET;
        fp[t] = prank[t] < NPR;
    }
    __syncthreads();
    const int base = tid * 16;
    int cr = 0, cp = 0;
#pragma unroll
    for (int e = 0; e < 16; ++e) { cr += fr[base + e]; cp += fp[base + e]; }
    sr[tid] = cr; sp[tid] = cp;
    __syncthreads();
    int pr = 0, pp = 0;
    for (int j = 0; j < tid; ++j) { pr += sr[j]; pp += sp[j]; }
#pragma unroll
    for (int e = 0; e < 16; ++e) {
        int i = base + e;
        if (fr[i]) { out_imps[pr] = (float)i; imp_rows[pr] = i; ++pr; }
        if (fp[i]) { out_prune[pp] = (float)i; prune_cols[pp] = i; ++pp; }
    }
}

__global__ __launch_bounds__(256) void argmax_part(
    const float* __restrict__ attn, const int* __restrict__ imp_rows,
    float* __restrict__ pbest, int* __restrict__ pbi)
{
    __shared__ int rows[CHUNK];
    const int tid = threadIdx.x;
    const int rc = blockIdx.y;
    const int r0 = rc * CHUNK;
    const int nr = min(KRET - r0, CHUNK);
    for (int t = tid; t < nr; t += 256) rows[t] = imp_rows[r0 + t];
    __syncthreads();
    const int j = blockIdx.x * 256 + tid;
    float best = -INFINITY;
    int bi = 0;
    for (int rr = 0; rr < nr; ++rr) {
        float val = attn[(size_t)rows[rr] * NT + j];
        if (val > best) { best = val; bi = r0 + rr; }
    }
    pbest[(size_t)rc * NT + j] = best;
    pbi[(size_t)rc * NT + j] = bi;
}

__global__ __launch_bounds__(256) void argmax_red(
    const float* __restrict__ pbest, const int* __restrict__ pbi,
    int* __restrict__ maxind)
{
    const int j = blockIdx.x * 256 + threadIdx.x;
    float best = -INFINITY;
    int bi = 0;
#pragma unroll
    for (int rc = 0; rc < 8; ++rc) {
        float val = pbest[(size_t)rc * NT + j];
        if (val > best) { best = val; bi = pbi[(size_t)rc * NT + j]; }
    }
    maxind[j] = bi;
}

__global__ __launch_bounds__(256) void finalize(
    const float* __restrict__ dist, const int* __restrict__ prune_cols,
    const int* __restrict__ maxind, float* __restrict__ out_imp,
    float* __restrict__ out_simi)
{
    int t = blockIdx.x * 256 + threadIdx.x;
    if (t < NT) out_imp[t] = dist[t];
    if (t < NPR) out_simi[t] = (float)maxind[prune_cols[t]];
}

extern "C" void kernel_launch(void* const* d_in, const int* in_sizes, int n_in,
                              void* d_out, int out_size, void* d_ws, size_t ws_size,
                              hipStream_t stream)
{
    const float* x  = (const float*)d_in[0];
    const float* Wq = (const float*)d_in[1];
    const float* Wk = (const float*)d_in[2];
    const float* Wv = (const float*)d_in[3];
    const float* Wo = (const float*)d_in[4];
    const float* bo = (const float*)d_in[5];
    float* out = (float*)d_out;

    const size_t QKT_EL = (size_t)NH * 256 * 3 * 16 * 32;   // 6.29M f16 per plane
    const size_t VP_EL  = (size_t)NH * 128 * 80 * 32;       // 5.24M bf16

    // ---- workspace layout (float units) ----
    float* ws = (float*)d_ws;
    size_t off = 0;
    float* attn = ws + off; off += (size_t)NT * NT;
    f16* Qt0 = (f16*)(ws + off); off += QKT_EL / 2;
    f16* Qt1 = (f16*)(ws + off); off += QKT_EL / 2;
    f16* Kt0 = (f16*)(ws + off); off += QKT_EL / 2;
    f16* Kt1 = (f16*)(ws + off); off += QKT_EL / 2;
    ushort_t* Vp = (ushort_t*)(ws + off); off += VP_EL / 2;
    size_t zero_floats = 4 * (QKT_EL / 2) + VP_EL / 2;      // Qt0..Vp contiguous
    ushort_t* otmpb = (ushort_t*)(ws + off); off += ((size_t)NT * DM) / 2;
    f16* X0 = (f16*)(ws + off); f16* X1 = X0 + (size_t)NT * DM; off += (size_t)NT * DM;
    f16* T0 = (f16*)(ws + off); f16* T1 = T0 + (size_t)DM * DM; off += (size_t)DM * DM;
    ushort_t* Wslot = (ushort_t*)(ws + off); off += ((size_t)DM * DM) / 2;
    float* invs    = ws + off; off += (size_t)NH * NT;
    ushort_t* part_pv = (ushort_t*)(ws + off); off += (size_t)CSB * 4 * NT * DH / 2;
    float* pbest   = ws + off; off += 8 * NT;
    int*   pbi     = (int*)(ws + off); off += 8 * NT;
    float* dist0 = ws + off; off += NT;
    float* dist1 = ws + off; off += NT;
    float* partial = ws + off; off += 32 * NT;
    int* rank      = (int*)(ws + off); off += NT;
    int* prank     = (int*)(ws + off); off += NT;
    int* imp_rows  = (int*)(ws + off); off += 2048;
    int* prune_cols= (int*)(ws + off); off += 2560;
    int* maxind    = (int*)(ws + off); off += NT;

    // setup-only alias inside attn region (dead before fused5 quad0 writes)
    ushort_t* xb = (ushort_t*)attn;

    // output layout
    float* out_out   = out;
    float* out_imp   = out + (size_t)NT * DM;
    float* out_imps  = out_imp + NT;
    float* out_prune = out_imps + KRET;
    float* out_simi  = out_prune + NPR;

    // ---- setup ----
    hipMemsetAsync(Qt0, 0, zero_floats * sizeof(float), stream);  // zero-pad tiles
    split_x<<<2048, 256, 0, stream>>>(x, X0, X1, xb, NT * DM);

    dim3 gT(DM / 32, DM / 32);
    dim3 gP(DM / 64, NT / 128);
    transposeW_split<<<gT, 256, 0, stream>>>(Wq, T0, T1, DM);
    proj_split3<<<gP, 256, 0, stream>>>(X0, X1, T0, T1, Qt0, Qt1, SCALE);
    transposeW_split<<<gT, 256, 0, stream>>>(Wk, T0, T1, DM);
    proj_split3<<<gP, 256, 0, stream>>>(X0, X1, T0, T1, Kt0, Kt1, 1.0f);

    transposeW_bf16<<<gT, 256, 0, stream>>>(Wv, Wslot, DM);
    gemm_bf16_lds<<<gP, 256, 0, stream>>>(xb, Wslot, nullptr, Vp, 2, DM, DM);

    // ---- pass A: inverse row sums (LDS-staged K, dense) ----
    rowsum4<<<dim3(NT / 64, NH), 256, 0, stream>>>(Qt0, Qt1, Kt0, Kt1, invs);

    // ---- pass B: fused attention, 4 heads per launch ----
    for (int hq = 0; hq < NH / 4; ++hq) {
        fused5<<<dim3(CSB, NT / 64), 256, 0, stream>>>(
            Qt0, Qt1, Kt0, Kt1, invs, Vp, attn, part_pv, hq, hq == 0 ? 1 : 0);
        pv_reduce4h<<<(4 * NT * DH + 255) / 256, 256, 0, stream>>>(part_pv, otmpb, hq);
    }

    // ---- output projection ----
    transposeW_bf16<<<gT, 256, 0, stream>>>(Wo, Wslot, DM);
    gemm_bf16_lds<<<gP, 256, 0, stream>>>(otmpb, Wslot, bo, out_out, 0, DM, DM);

    // ---- pagerank ----
    init_dist<<<16, 256, 0, stream>>>(dist0);
    float* da = dist0;
    float* db = dist1;
    for (int it = 0; it < 5; ++it) {
        power_a<<<dim3(16, 32), 256, 0, stream>>>(attn, da, partial);
        power_b<<<16, 256, 0, stream>>>(partial, db);
        float* t = da; da = db; db = t;
    }

    // ---- top-k ----
    hipMemsetAsync(rank, 0, 2 * NT * sizeof(int), stream);
    rank_count<<<dim3(16, 16), 256, 0, stream>>>(da, rank, prank);
    scatter_topk2<<<1, 256, 0, stream>>>(rank, prank, out_imps, out_prune,
                                         imp_rows, prune_cols);
    argmax_part<<<dim3(16, 8), 256, 0, stream>>>(attn, imp_rows, pbest, pbi);
    argmax_red<<<16, 256, 0, stream>>>(pbest, pbi, maxind);
    finalize<<<16, 256, 0, stream>>>(da, prune_cols, maxind, out_imp, out_simi);
}

// Round 10
// 1422.098 us; speedup vs baseline: 1.0242x; 1.0161x over previous
//
#include <hip/hip_runtime.h>
#include <math.h>

#define NT 4096
#define DM 1152
#define NH 16
#define DH 72
#define KRET 1638
#define NPR (NT - KRET)
#define CSB 8
#define CHUNK 205
#define SCALE 0.11785113019775793f
#define RSPLIT 2048.0f
#define INV_RSPLIT 4.8828125e-4f

typedef __attribute__((ext_vector_type(8))) short bf16x8;
typedef _Float16 f16;
typedef __attribute__((ext_vector_type(8))) _Float16 f16x8;
typedef __attribute__((ext_vector_type(4))) float f32x4;
typedef unsigned short ushort_t;

#define MFMA16(a, b, c) __builtin_amdgcn_mfma_f32_16x16x32_f16(a, b, c, 0, 0, 0)
#define MFMABF(a, b, c) __builtin_amdgcn_mfma_f32_16x16x32_bf16(a, b, c, 0, 0, 0)

__device__ inline ushort_t f2b(float f) {
    union { float f; unsigned int u; } v; v.f = f;
    unsigned int u = v.u;
    return (ushort_t)((u + 0x7FFFu + ((u >> 16) & 1u)) >> 16);
}

// tiled Q/K address: [NH][rowblk 256][ks 3][r 16][ki 32]
__device__ inline size_t qkAddr(int h, int row, int ks, int ki) {
    return ((((size_t)h * 256 + (row >> 4)) * 3 + ks) * 16 + (row & 15)) * 32 + ki;
}

// ---------- split x into fp16 hi/lo(x2048) planes + bf16 copy ----------------
__global__ __launch_bounds__(256) void split_x(
    const float* __restrict__ in, f16* __restrict__ x0, f16* __restrict__ x1,
    ushort_t* __restrict__ xb, int nElem)
{
    int i = blockIdx.x * 256 + threadIdx.x;
    int stride = gridDim.x * 256;
    for (; i < nElem; i += stride) {
        float v = in[i];
        f16 h0 = (f16)v;
        float res = (v - (float)h0) * RSPLIT;
        x0[i] = h0;
        x1[i] = (f16)res;
        xb[i] = f2b(v);
    }
}

__global__ __launch_bounds__(256) void transposeW_split(
    const float* __restrict__ W, f16* __restrict__ T0, f16* __restrict__ T1, int n)
{
    __shared__ float t[32][33];
    int bx = blockIdx.x * 32, by = blockIdx.y * 32;
    int tx = threadIdx.x & 31, ty = threadIdx.x >> 5;
    for (int i = ty; i < 32; i += 8)
        t[i][tx] = W[(size_t)(by + i) * n + bx + tx];
    __syncthreads();
    for (int i = ty; i < 32; i += 8) {
        float v = t[tx][i];
        f16 h0 = (f16)v;
        float res = (v - (float)h0) * RSPLIT;
        T0[(size_t)(bx + i) * n + by + tx] = h0;
        T1[(size_t)(bx + i) * n + by + tx] = (f16)res;
    }
}

__global__ __launch_bounds__(256) void transposeW_bf16(
    const float* __restrict__ W, ushort_t* __restrict__ WT, int n)
{
    __shared__ ushort_t t[32][33];
    int bx = blockIdx.x * 32, by = blockIdx.y * 32;
    int tx = threadIdx.x & 31, ty = threadIdx.x >> 5;
    for (int i = ty; i < 32; i += 8)
        t[i][tx] = f2b(W[(size_t)(by + i) * n + bx + tx]);
    __syncthreads();
    for (int i = ty; i < 32; i += 8)
        WT[(size_t)(bx + i) * n + by + tx] = t[tx][i];
}

// ---------- LDS-tiled split projection -> MFMA-tiled per-head output ---------
__global__ __launch_bounds__(256) void proj_split3(
    const f16* __restrict__ A0, const f16* __restrict__ A1,
    const f16* __restrict__ B0, const f16* __restrict__ B1,
    f16* __restrict__ Qt0, f16* __restrict__ Qt1, float scl)
{
    __shared__ __align__(16) f16 As0[128][40];
    __shared__ __align__(16) f16 As1[128][40];
    __shared__ __align__(16) f16 Bs0[64][40];
    __shared__ __align__(16) f16 Bs1[64][40];
    const int tid = threadIdx.x;
    const int wave = tid >> 6, lane = tid & 63;
    const int r = lane & 15, g = lane >> 4;
    const int row0 = blockIdx.y * 128;
    const int col0 = blockIdx.x * 64;
    f32x4 accM[2][4] = {}, accC[2][4] = {};
    for (int k0 = 0; k0 < DM; k0 += 32) {
        for (int idx = tid; idx < 128 * 4; idx += 256) {
            int row = idx >> 2, c = idx & 3;
            size_t src = (size_t)(row0 + row) * DM + k0 + c * 8;
            *(f16x8*)&As0[row][c * 8] = *(const f16x8*)(A0 + src);
            *(f16x8*)&As1[row][c * 8] = *(const f16x8*)(A1 + src);
        }
        for (int idx = tid; idx < 64 * 4; idx += 256) {
            int row = idx >> 2, c = idx & 3;
            size_t src = (size_t)(col0 + row) * DM + k0 + c * 8;
            *(f16x8*)&Bs0[row][c * 8] = *(const f16x8*)(B0 + src);
            *(f16x8*)&Bs1[row][c * 8] = *(const f16x8*)(B1 + src);
        }
        __syncthreads();
        f16x8 a0[2], a1[2], b0[4], b1[4];
#pragma unroll
        for (int rf = 0; rf < 2; ++rf) {
            a0[rf] = *(const f16x8*)&As0[wave * 32 + rf * 16 + r][g * 8];
            a1[rf] = *(const f16x8*)&As1[wave * 32 + rf * 16 + r][g * 8];
        }
#pragma unroll
        for (int cf = 0; cf < 4; ++cf) {
            b0[cf] = *(const f16x8*)&Bs0[cf * 16 + r][g * 8];
            b1[cf] = *(const f16x8*)&Bs1[cf * 16 + r][g * 8];
        }
#pragma unroll
        for (int rf = 0; rf < 2; ++rf)
#pragma unroll
            for (int cf = 0; cf < 4; ++cf) {
                accM[rf][cf] = MFMA16(a0[rf], b0[cf], accM[rf][cf]);
                accC[rf][cf] = MFMA16(a0[rf], b1[cf], accC[rf][cf]);
                accC[rf][cf] = MFMA16(a1[rf], b0[cf], accC[rf][cf]);
            }
        __syncthreads();
    }
#pragma unroll
    for (int rf = 0; rf < 2; ++rf)
#pragma unroll
        for (int cf = 0; cf < 4; ++cf) {
            int col = col0 + cf * 16 + r;
            int head = col / DH;
            int c = col - head * DH;
            int ks = c >> 5, ki = c & 31;
#pragma unroll
            for (int j = 0; j < 4; ++j) {
                int row = row0 + wave * 32 + rf * 16 + g * 4 + j;
                float v = (accM[rf][cf][j] + accC[rf][cf][j] * INV_RSPLIT) * scl;
                f16 h0 = (f16)v;
                float res = (v - (float)h0) * RSPLIT;
                size_t addr = qkAddr(head, row, ks, ki);
                Qt0[addr] = h0;
                Qt1[addr] = (f16)res;
            }
        }
}

// ---------- LDS-tiled bf16 MFMA GEMM; mode 0 = fp32 flat, 2 = Vp tiled -------
__global__ __launch_bounds__(256) void gemm_bf16_lds(
    const ushort_t* __restrict__ A, const ushort_t* __restrict__ BT,
    const float* __restrict__ bias, void* __restrict__ C, int mode,
    int Nn, int K)
{
    __shared__ __align__(16) ushort_t As[128][40];
    __shared__ __align__(16) ushort_t Bs[64][40];
    const int tid = threadIdx.x;
    const int wave = tid >> 6, lane = tid & 63;
    const int r = lane & 15, g = lane >> 4;
    const int row0 = blockIdx.y * 128;
    const int col0 = blockIdx.x * 64;
    f32x4 acc[2][4] = {};
    for (int k0 = 0; k0 < K; k0 += 32) {
        for (int idx = tid; idx < 128 * 4; idx += 256) {
            int row = idx >> 2, c = idx & 3;
            *(bf16x8*)&As[row][c * 8] = *(const bf16x8*)(A + (size_t)(row0 + row) * K + k0 + c * 8);
        }
        for (int idx = tid; idx < 64 * 4; idx += 256) {
            int row = idx >> 2, c = idx & 3;
            *(bf16x8*)&Bs[row][c * 8] = *(const bf16x8*)(BT + (size_t)(col0 + row) * K + k0 + c * 8);
        }
        __syncthreads();
        bf16x8 a[2], b[4];
#pragma unroll
        for (int rf = 0; rf < 2; ++rf)
            a[rf] = *(const bf16x8*)&As[wave * 32 + rf * 16 + r][g * 8];
#pragma unroll
        for (int cf = 0; cf < 4; ++cf)
            b[cf] = *(const bf16x8*)&Bs[cf * 16 + r][g * 8];
#pragma unroll
        for (int rf = 0; rf < 2; ++rf)
#pragma unroll
            for (int cf = 0; cf < 4; ++cf)
                acc[rf][cf] = MFMABF(a[rf], b[cf], acc[rf][cf]);
        __syncthreads();
    }
#pragma unroll
    for (int rf = 0; rf < 2; ++rf)
#pragma unroll
        for (int cf = 0; cf < 4; ++cf) {
            int col = col0 + cf * 16 + r;
            float bv = bias ? bias[col] : 0.f;
#pragma unroll
            for (int j = 0; j < 4; ++j) {
                int row = row0 + wave * 32 + rf * 16 + g * 4 + j;
                float vv = acc[rf][cf][j] + bv;
                if (mode == 2) {
                    int head = col / DH;
                    int d = col - head * DH;
                    size_t addr = (((size_t)head * 128 + (row >> 5)) * 80 + d) * 32 + (row & 31);
                    ((ushort_t*)C)[addr] = f2b(vv);
                } else {
                    ((float*)C)[(size_t)row * Nn + col] = vv;
                }
            }
        }
}

// ---------- pass A: rowsum + PV with unnormalized exp; per head --------------
// grid (NT/64, NH), 256 threads. rs accumulation bit-identical to rowsum4.
// out_h(i,:) = (sum_j exp(s_ij) * V_j) * inv_i written directly to otmpb.
__global__ __launch_bounds__(256) void rowsum_pv(
    const f16* __restrict__ Qt0, const f16* __restrict__ Qt1,
    const f16* __restrict__ Kt0, const f16* __restrict__ Kt1,
    const ushort_t* __restrict__ Vp,
    float* __restrict__ invs, ushort_t* __restrict__ otmpb)
{
    __shared__ __align__(16) f16 KL[2][6144];   // [plane][12 tiles of 512]
    __shared__ ushort_t Pt[64][88];
    const int tid = threadIdx.x;
    const int wv = tid >> 6, lane = tid & 63;
    const int r = lane & 15, g = lane >> 4;
    const int h = blockIdx.y;
    const int rowblk = blockIdx.x * 4 + wv;
    f16x8 a0[3], a1[3];
#pragma unroll
    for (int ks = 0; ks < 3; ++ks) {
        size_t o = ((((size_t)h * 256 + rowblk) * 3 + ks) * 16) * 32 + r * 32 + g * 8;
        a0[ks] = *(const f16x8*)(Qt0 + o);
        a1[ks] = *(const f16x8*)(Qt1 + o);
    }
    float rs0 = 0.f, rs1 = 0.f, rs2 = 0.f, rs3 = 0.f;
    f32x4 oacc[5] = {};
    for (int ct = 0; ct < 64; ++ct) {
        __syncthreads();
        const size_t ctBase = ((size_t)h * 256 + ct * 4) * 1536;
#pragma unroll
        for (int s = 0; s < 6; ++s) {
            int wc = s * 4 + wv;             // 0..23 wave-chunks of 1024B
            int plane = wc >= 12;
            int cip = wc - plane * 12;
            const f16* src = (plane ? Kt1 : Kt0) + ctBase + cip * 512 + lane * 8;
            *(f16x8*)&KL[plane][cip * 512 + lane * 8] = *(const f16x8*)src;
        }
        __syncthreads();
        f32x4 accM[4] = {}, accC[4] = {};
#pragma unroll
        for (int ks = 0; ks < 3; ++ks) {
#pragma unroll
            for (int cf = 0; cf < 4; ++cf) {
                f16x8 b0 = *(const f16x8*)&KL[0][(cf * 3 + ks) * 512 + r * 32 + g * 8];
                f16x8 b1 = *(const f16x8*)&KL[1][(cf * 3 + ks) * 512 + r * 32 + g * 8];
                accM[cf] = MFMA16(a0[ks], b0, accM[cf]);
                accC[cf] = MFMA16(a0[ks], b1, accC[cf]);
                accC[cf] = MFMA16(a1[ks], b0, accC[cf]);
            }
        }
        // exp, rowsum accumulate (order identical to rowsum4), stash e to Pt
#pragma unroll
        for (int cf = 0; cf < 4; ++cf) {
            float e0 = __expf(accM[cf][0] + accC[cf][0] * INV_RSPLIT);
            float e1 = __expf(accM[cf][1] + accC[cf][1] * INV_RSPLIT);
            float e2 = __expf(accM[cf][2] + accC[cf][2] * INV_RSPLIT);
            float e3 = __expf(accM[cf][3] + accC[cf][3] * INV_RSPLIT);
            rs0 += e0; rs1 += e1; rs2 += e2; rs3 += e3;
            Pt[wv * 16 + g * 4 + 0][cf * 16 + r] = f2b(e0);
            Pt[wv * 16 + g * 4 + 1][cf * 16 + r] = f2b(e1);
            Pt[wv * 16 + g * 4 + 2][cf * 16 + r] = f2b(e2);
            Pt[wv * 16 + g * 4 + 3][cf * 16 + r] = f2b(e3);
        }
        // PV with unnormalized e (wave-private Pt rows; no barrier needed)
        const int kt0 = ct * 2;
#pragma unroll
        for (int ks2 = 0; ks2 < 2; ++ks2) {
            bf16x8 pa = *(const bf16x8*)&Pt[wv * 16 + r][ks2 * 32 + g * 8];
#pragma unroll
            for (int t = 0; t < 5; ++t) {
                int col = t * 16 + r;
                size_t vo = (((size_t)h * 128 + kt0 + ks2) * 80 + col) * 32 + g * 8;
                bf16x8 b = *(const bf16x8*)(Vp + vo);
                oacc[t] = MFMABF(pa, b, oacc[t]);
            }
        }
    }
#pragma unroll
    for (int m = 1; m <= 8; m <<= 1) {
        rs0 += __shfl_xor(rs0, m);
        rs1 += __shfl_xor(rs1, m);
        rs2 += __shfl_xor(rs2, m);
        rs3 += __shfl_xor(rs3, m);
    }
    float inv0 = 1.0f / rs0, inv1 = 1.0f / rs1, inv2 = 1.0f / rs2, inv3 = 1.0f / rs3;
    if (r == 0) {
        int rbase = rowblk * 16 + g * 4;
        invs[(size_t)h * NT + rbase + 0] = inv0;
        invs[(size_t)h * NT + rbase + 1] = inv1;
        invs[(size_t)h * NT + rbase + 2] = inv2;
        invs[(size_t)h * NT + rbase + 3] = inv3;
    }
    float invj[4] = { inv0, inv1, inv2, inv3 };
#pragma unroll
    for (int t = 0; t < 5; ++t) {
        int col = t * 16 + r;
        if (col < DH) {
#pragma unroll
            for (int j = 0; j < 4; ++j) {
                int row = rowblk * 16 + g * 4 + j;
                otmpb[(size_t)row * DM + h * DH + col] = f2b(oacc[t][j] * invj[j]);
            }
        }
    }
}

// ---------- pass B: attn = (1/16) sum_h exp(s)*inv; write-once ---------------
// grid (CSB, NT/64). ct outer, head-pair inner; attn_acc in 16 regs.
__global__ __launch_bounds__(256) void attn_sum(
    const f16* __restrict__ Qt0, const f16* __restrict__ Qt1,
    const f16* __restrict__ Kt0, const f16* __restrict__ Kt1,
    const float* __restrict__ invs, float* __restrict__ attn)
{
    __shared__ __align__(16) f16 KL[4][6144];   // [pairhead*2+plane][12 tiles]
    const int tid = threadIdx.x;
    const int wr = tid >> 6, lane = tid & 63;
    const int r = lane & 15, g = lane >> 4;
    const int cs = blockIdx.x;
    const int rowblk = blockIdx.y * 4 + wr;
    const int row0 = rowblk * 16;
    for (int ct = 0; ct < 8; ++ct) {
        const int colbase = cs * 512 + ct * 64;
        const int cb0 = colbase >> 4;
        float aacc[4][4] = {};
        for (int hp = 0; hp < 8; ++hp) {
            __syncthreads();
#pragma unroll
            for (int s = 0; s < 12; ++s) {
                int wc = s * 4 + wr;            // 0..47 wave-chunks of 1024B
                int seg = wc / 12;              // hh*2 + plane
                int cip = wc - seg * 12;
                int hh = seg >> 1, pl = seg & 1;
                const f16* base = pl ? Kt1 : Kt0;
                size_t srcOff = ((size_t)(hp * 2 + hh) * 256 + cb0) * 1536
                              + cip * 512 + lane * 8;
                *(f16x8*)&KL[seg][cip * 512 + lane * 8] = *(const f16x8*)(base + srcOff);
            }
            __syncthreads();
#pragma unroll
            for (int hh2 = 0; hh2 < 2; ++hh2) {
                const int h = hp * 2 + hh2;
                f16x8 a0[3], a1[3];
#pragma unroll
                for (int ks = 0; ks < 3; ++ks) {
                    size_t o = ((((size_t)h * 256 + rowblk) * 3 + ks) * 16) * 32 + r * 32 + g * 8;
                    a0[ks] = *(const f16x8*)(Qt0 + o);
                    a1[ks] = *(const f16x8*)(Qt1 + o);
                }
                float vinv[4];
#pragma unroll
                for (int j = 0; j < 4; ++j)
                    vinv[j] = invs[(size_t)h * NT + row0 + g * 4 + j];
                f32x4 accM[4] = {}, accC[4] = {};
#pragma unroll
                for (int ks = 0; ks < 3; ++ks) {
#pragma unroll
                    for (int cf = 0; cf < 4; ++cf) {
                        f16x8 b0 = *(const f16x8*)&KL[hh2 * 2 + 0][(cf * 3 + ks) * 512 + r * 32 + g * 8];
                        f16x8 b1 = *(const f16x8*)&KL[hh2 * 2 + 1][(cf * 3 + ks) * 512 + r * 32 + g * 8];
                        accM[cf] = MFMA16(a0[ks], b0, accM[cf]);
                        accC[cf] = MFMA16(a0[ks], b1, accC[cf]);
                        accC[cf] = MFMA16(a1[ks], b0, accC[cf]);
                    }
                }
#pragma unroll
                for (int cf = 0; cf < 4; ++cf) {
#pragma unroll
                    for (int j = 0; j < 4; ++j) {
                        float p = __expf(accM[cf][j] + accC[cf][j] * INV_RSPLIT) * vinv[j];
                        aacc[cf][j] += p;
                    }
                }
            }
        }
        // write attn once (no rmw)
#pragma unroll
        for (int cf = 0; cf < 4; ++cf) {
#pragma unroll
            for (int j = 0; j < 4; ++j) {
                int row = row0 + g * 4 + j;
                attn[(size_t)row * NT + colbase + cf * 16 + r] = aacc[cf][j] * 0.0625f;
            }
        }
    }
}

// ---------- pagerank power iteration (fp32, unchanged) -----------------------
__global__ __launch_bounds__(256) void init_dist(float* __restrict__ d)
{
    int t = blockIdx.x * 256 + threadIdx.x;
    if (t < NT) d[t] = 1.0f / NT;
}

__global__ __launch_bounds__(256) void power_a(
    const float* __restrict__ attn, const float* __restrict__ din,
    float* __restrict__ part)
{
    int j = blockIdx.x * 256 + threadIdx.x;
    int i0 = blockIdx.y * 128;
    float acc = 0.f;
    for (int i = i0; i < i0 + 128; ++i)
        acc += din[i] * attn[(size_t)i * NT + j];
    part[(size_t)blockIdx.y * NT + j] = acc;
}

__global__ __launch_bounds__(256) void power_b(
    const float* __restrict__ part, float* __restrict__ dout)
{
    int j = blockIdx.x * 256 + threadIdx.x;
    float acc = 0.f;
    for (int ib = 0; ib < 32; ++ib) acc += part[(size_t)ib * NT + j];
    dout[j] = acc;
}

// ---------- top-k: tiled rank counting (deterministic int atomics) -----------
__global__ __launch_bounds__(256) void rank_count(
    const float* __restrict__ imp, int* __restrict__ rank, int* __restrict__ prank)
{
    __shared__ float sj[256];
    const int tid = threadIdx.x;
    const int jb = blockIdx.y * 256;
    sj[tid] = imp[jb + tid];
    __syncthreads();
    const int i = blockIdx.x * 256 + tid;
    const float mv = imp[i];
    int r = 0, rp = 0;
    for (int jj = 0; jj < 256; ++jj) {
        float vj = sj[jj];
        int j = jb + jj;
        int tie_low = (vj == mv) && (j < i);
        r  += (vj > mv) || tie_low;
        rp += (vj < mv) || tie_low;
    }
    atomicAdd(&rank[i], r);
    atomicAdd(&prank[i], rp);
}

__global__ __launch_bounds__(256) void scatter_topk2(
    const int* __restrict__ rank, const int* __restrict__ prank,
    float* __restrict__ out_imps, float* __restrict__ out_prune,
    int* __restrict__ imp_rows, int* __restrict__ prune_cols)
{
    __shared__ unsigned char fr[NT];
    __shared__ unsigned char fp[NT];
    __shared__ int sr[256], sp[256];
    const int tid = threadIdx.x;
    for (int t = tid; t < NT; t += 256) {
        fr[t] = rank[t] < KRET;
        fp[t] = prank[t] < NPR;
    }
    __syncthreads();
    const int base = tid * 16;
    int cr = 0, cp = 0;
#pragma unroll
    for (int e = 0; e < 16; ++e) { cr += fr[base + e]; cp += fp[base + e]; }
    sr[tid] = cr; sp[tid] = cp;
    __syncthreads();
    int pr = 0, pp = 0;
    for (int j = 0; j < tid; ++j) { pr += sr[j]; pp += sp[j]; }
#pragma unroll
    for (int e = 0; e < 16; ++e) {
        int i = base + e;
        if (fr[i]) { out_imps[pr] = (float)i; imp_rows[pr] = i; ++pr; }
        if (fp[i]) { out_prune[pp] = (float)i; prune_cols[pp] = i; ++pp; }
    }
}

__global__ __launch_bounds__(256) void argmax_part(
    const float* __restrict__ attn, const int* __restrict__ imp_rows,
    float* __restrict__ pbest, int* __restrict__ pbi)
{
    __shared__ int rows[CHUNK];
    const int tid = threadIdx.x;
    const int rc = blockIdx.y;
    const int r0 = rc * CHUNK;
    const int nr = min(KRET - r0, CHUNK);
    for (int t = tid; t < nr; t += 256) rows[t] = imp_rows[r0 + t];
    __syncthreads();
    const int j = blockIdx.x * 256 + tid;
    float best = -INFINITY;
    int bi = 0;
    for (int rr = 0; rr < nr; ++rr) {
        float val = attn[(size_t)rows[rr] * NT + j];
        if (val > best) { best = val; bi = r0 + rr; }
    }
    pbest[(size_t)rc * NT + j] = best;
    pbi[(size_t)rc * NT + j] = bi;
}

__global__ __launch_bounds__(256) void argmax_red(
    const float* __restrict__ pbest, const int* __restrict__ pbi,
    int* __restrict__ maxind)
{
    const int j = blockIdx.x * 256 + threadIdx.x;
    float best = -INFINITY;
    int bi = 0;
#pragma unroll
    for (int rc = 0; rc < 8; ++rc) {
        float val = pbest[(size_t)rc * NT + j];
        if (val > best) { best = val; bi = pbi[(size_t)rc * NT + j]; }
    }
    maxind[j] = bi;
}

__global__ __launch_bounds__(256) void finalize(
    const float* __restrict__ dist, const int* __restrict__ prune_cols,
    const int* __restrict__ maxind, float* __restrict__ out_imp,
    float* __restrict__ out_simi)
{
    int t = blockIdx.x * 256 + threadIdx.x;
    if (t < NT) out_imp[t] = dist[t];
    if (t < NPR) out_simi[t] = (float)maxind[prune_cols[t]];
}

extern "C" void kernel_launch(void* const* d_in, const int* in_sizes, int n_in,
                              void* d_out, int out_size, void* d_ws, size_t ws_size,
                              hipStream_t stream)
{
    const float* x  = (const float*)d_in[0];
    const float* Wq = (const float*)d_in[1];
    const float* Wk = (const float*)d_in[2];
    const float* Wv = (const float*)d_in[3];
    const float* Wo = (const float*)d_in[4];
    const float* bo = (const float*)d_in[5];
    float* out = (float*)d_out;

    const size_t QKT_EL = (size_t)NH * 256 * 3 * 16 * 32;   // 6.29M f16 per plane
    const size_t VP_EL  = (size_t)NH * 128 * 80 * 32;       // 5.24M bf16

    // ---- workspace layout (float units) ----
    float* ws = (float*)d_ws;
    size_t off = 0;
    float* attn = ws + off; off += (size_t)NT * NT;
    f16* Qt0 = (f16*)(ws + off); off += QKT_EL / 2;
    f16* Qt1 = (f16*)(ws + off); off += QKT_EL / 2;
    f16* Kt0 = (f16*)(ws + off); off += QKT_EL / 2;
    f16* Kt1 = (f16*)(ws + off); off += QKT_EL / 2;
    ushort_t* Vp = (ushort_t*)(ws + off); off += VP_EL / 2;
    size_t zero_floats = 4 * (QKT_EL / 2) + VP_EL / 2;      // Qt0..Vp contiguous
    ushort_t* otmpb = (ushort_t*)(ws + off); off += ((size_t)NT * DM) / 2;
    f16* X0 = (f16*)(ws + off); f16* X1 = X0 + (size_t)NT * DM; off += (size_t)NT * DM;
    f16* T0 = (f16*)(ws + off); f16* T1 = T0 + (size_t)DM * DM; off += (size_t)DM * DM;
    ushort_t* Wslot = (ushort_t*)(ws + off); off += ((size_t)DM * DM) / 2;
    float* invs    = ws + off; off += (size_t)NH * NT;
    float* pbest   = ws + off; off += 8 * NT;
    int*   pbi     = (int*)(ws + off); off += 8 * NT;
    float* dist0 = ws + off; off += NT;
    float* dist1 = ws + off; off += NT;
    float* partial = ws + off; off += 32 * NT;
    int* rank      = (int*)(ws + off); off += NT;
    int* prank     = (int*)(ws + off); off += NT;
    int* imp_rows  = (int*)(ws + off); off += 2048;
    int* prune_cols= (int*)(ws + off); off += 2560;
    int* maxind    = (int*)(ws + off); off += NT;

    // setup-only alias inside attn region (dead before attn_sum writes)
    ushort_t* xb = (ushort_t*)attn;

    // output layout
    float* out_out   = out;
    float* out_imp   = out + (size_t)NT * DM;
    float* out_imps  = out_imp + NT;
    float* out_prune = out_imps + KRET;
    float* out_simi  = out_prune + NPR;

    // ---- setup ----
    hipMemsetAsync(Qt0, 0, zero_floats * sizeof(float), stream);  // zero-pad tiles
    split_x<<<2048, 256, 0, stream>>>(x, X0, X1, xb, NT * DM);

    dim3 gT(DM / 32, DM / 32);
    dim3 gP(DM / 64, NT / 128);
    transposeW_split<<<gT, 256, 0, stream>>>(Wq, T0, T1, DM);
    proj_split3<<<gP, 256, 0, stream>>>(X0, X1, T0, T1, Qt0, Qt1, SCALE);
    transposeW_split<<<gT, 256, 0, stream>>>(Wk, T0, T1, DM);
    proj_split3<<<gP, 256, 0, stream>>>(X0, X1, T0, T1, Kt0, Kt1, 1.0f);

    transposeW_bf16<<<gT, 256, 0, stream>>>(Wv, Wslot, DM);
    gemm_bf16_lds<<<gP, 256, 0, stream>>>(xb, Wslot, nullptr, Vp, 2, DM, DM);

    // ---- pass A: rowsums + PV (unnormalized exp, normalized in epilogue) ----
    rowsum_pv<<<dim3(NT / 64, NH), 256, 0, stream>>>(Qt0, Qt1, Kt0, Kt1, Vp,
                                                     invs, otmpb);

    // ---- pass B: attn head-sum, single launch, write-once ----
    attn_sum<<<dim3(CSB, NT / 64), 256, 0, stream>>>(Qt0, Qt1, Kt0, Kt1, invs, attn);

    // ---- output projection ----
    transposeW_bf16<<<gT, 256, 0, stream>>>(Wo, Wslot, DM);
    gemm_bf16_lds<<<gP, 256, 0, stream>>>(otmpb, Wslot, bo, out_out, 0, DM, DM);

    // ---- pagerank ----
    init_dist<<<16, 256, 0, stream>>>(dist0);
    float* da = dist0;
    float* db = dist1;
    for (int it = 0; it < 5; ++it) {
        power_a<<<dim3(16, 32), 256, 0, stream>>>(attn, da, partial);
        power_b<<<16, 256, 0, stream>>>(partial, db);
        float* t = da; da = db; db = t;
    }

    // ---- top-k ----
    hipMemsetAsync(rank, 0, 2 * NT * sizeof(int), stream);
    rank_count<<<dim3(16, 16), 256, 0, stream>>>(da, rank, prank);
    scatter_topk2<<<1, 256, 0, stream>>>(rank, prank, out_imps, out_prune,
                                         imp_rows, prune_cols);
    argmax_part<<<dim3(16, 8), 256, 0, stream>>>(attn, imp_rows, pbest, pbi);
    argmax_red<<<16, 256, 0, stream>>>(pbest, pbi, maxind);
    finalize<<<16, 256, 0, stream>>>(da, prune_cols, maxind, out_imp, out_simi);
}

// Round 11
// 1136.017 us; speedup vs baseline: 1.2822x; 1.2518x over previous
//
#include <hip/hip_runtime.h>
#include <math.h>

#define NT 4096
#define DM 1152
#define NH 16
#define DH 72
#define KRET 1638
#define NPR (NT - KRET)
#define CSB 8
#define CHUNK 205
#define SCALE 0.11785113019775793f
#define RSPLIT 2048.0f
#define INV_RSPLIT 4.8828125e-4f

typedef __attribute__((ext_vector_type(8))) short bf16x8;
typedef _Float16 f16;
typedef __attribute__((ext_vector_type(8))) _Float16 f16x8;
typedef __attribute__((ext_vector_type(4))) float f32x4;
typedef unsigned short ushort_t;

#define MFMA16(a, b, c) __builtin_amdgcn_mfma_f32_16x16x32_f16(a, b, c, 0, 0, 0)
#define MFMABF(a, b, c) __builtin_amdgcn_mfma_f32_16x16x32_bf16(a, b, c, 0, 0, 0)

__device__ inline ushort_t f2b(float f) {
    union { float f; unsigned int u; } v; v.f = f;
    unsigned int u = v.u;
    return (ushort_t)((u + 0x7FFFu + ((u >> 16) & 1u)) >> 16);
}

// tiled Q/K address: [NH][rowblk 256][ks 3][r 16][ki 32]
__device__ inline size_t qkAddr(int h, int row, int ks, int ki) {
    return ((((size_t)h * 256 + (row >> 4)) * 3 + ks) * 16 + (row & 15)) * 32 + ki;
}

// ---------- split x into fp16 hi/lo(x2048) planes + bf16 copy ----------------
__global__ __launch_bounds__(256) void split_x(
    const float* __restrict__ in, f16* __restrict__ x0, f16* __restrict__ x1,
    ushort_t* __restrict__ xb, int nElem)
{
    int i = blockIdx.x * 256 + threadIdx.x;
    int stride = gridDim.x * 256;
    for (; i < nElem; i += stride) {
        float v = in[i];
        f16 h0 = (f16)v;
        float res = (v - (float)h0) * RSPLIT;
        x0[i] = h0;
        x1[i] = (f16)res;
        xb[i] = f2b(v);
    }
}

__global__ __launch_bounds__(256) void transposeW_split(
    const float* __restrict__ W, f16* __restrict__ T0, f16* __restrict__ T1, int n)
{
    __shared__ float t[32][33];
    int bx = blockIdx.x * 32, by = blockIdx.y * 32;
    int tx = threadIdx.x & 31, ty = threadIdx.x >> 5;
    for (int i = ty; i < 32; i += 8)
        t[i][tx] = W[(size_t)(by + i) * n + bx + tx];
    __syncthreads();
    for (int i = ty; i < 32; i += 8) {
        float v = t[tx][i];
        f16 h0 = (f16)v;
        float res = (v - (float)h0) * RSPLIT;
        T0[(size_t)(bx + i) * n + by + tx] = h0;
        T1[(size_t)(bx + i) * n + by + tx] = (f16)res;
    }
}

__global__ __launch_bounds__(256) void transposeW_bf16(
    const float* __restrict__ W, ushort_t* __restrict__ WT, int n)
{
    __shared__ ushort_t t[32][33];
    int bx = blockIdx.x * 32, by = blockIdx.y * 32;
    int tx = threadIdx.x & 31, ty = threadIdx.x >> 5;
    for (int i = ty; i < 32; i += 8)
        t[i][tx] = f2b(W[(size_t)(by + i) * n + bx + tx]);
    __syncthreads();
    for (int i = ty; i < 32; i += 8)
        WT[(size_t)(bx + i) * n + by + tx] = t[tx][i];
}

// ---------- LDS-tiled split projection -> MFMA-tiled per-head output ---------
__global__ __launch_bounds__(256) void proj_split3(
    const f16* __restrict__ A0, const f16* __restrict__ A1,
    const f16* __restrict__ B0, const f16* __restrict__ B1,
    f16* __restrict__ Qt0, f16* __restrict__ Qt1, float scl)
{
    __shared__ __align__(16) f16 As0[128][40];
    __shared__ __align__(16) f16 As1[128][40];
    __shared__ __align__(16) f16 Bs0[64][40];
    __shared__ __align__(16) f16 Bs1[64][40];
    const int tid = threadIdx.x;
    const int wave = tid >> 6, lane = tid & 63;
    const int r = lane & 15, g = lane >> 4;
    const int row0 = blockIdx.y * 128;
    const int col0 = blockIdx.x * 64;
    f32x4 accM[2][4] = {}, accC[2][4] = {};
    for (int k0 = 0; k0 < DM; k0 += 32) {
        for (int idx = tid; idx < 128 * 4; idx += 256) {
            int row = idx >> 2, c = idx & 3;
            size_t src = (size_t)(row0 + row) * DM + k0 + c * 8;
            *(f16x8*)&As0[row][c * 8] = *(const f16x8*)(A0 + src);
            *(f16x8*)&As1[row][c * 8] = *(const f16x8*)(A1 + src);
        }
        for (int idx = tid; idx < 64 * 4; idx += 256) {
            int row = idx >> 2, c = idx & 3;
            size_t src = (size_t)(col0 + row) * DM + k0 + c * 8;
            *(f16x8*)&Bs0[row][c * 8] = *(const f16x8*)(B0 + src);
            *(f16x8*)&Bs1[row][c * 8] = *(const f16x8*)(B1 + src);
        }
        __syncthreads();
        f16x8 a0[2], a1[2], b0[4], b1[4];
#pragma unroll
        for (int rf = 0; rf < 2; ++rf) {
            a0[rf] = *(const f16x8*)&As0[wave * 32 + rf * 16 + r][g * 8];
            a1[rf] = *(const f16x8*)&As1[wave * 32 + rf * 16 + r][g * 8];
        }
#pragma unroll
        for (int cf = 0; cf < 4; ++cf) {
            b0[cf] = *(const f16x8*)&Bs0[cf * 16 + r][g * 8];
            b1[cf] = *(const f16x8*)&Bs1[cf * 16 + r][g * 8];
        }
#pragma unroll
        for (int rf = 0; rf < 2; ++rf)
#pragma unroll
            for (int cf = 0; cf < 4; ++cf) {
                accM[rf][cf] = MFMA16(a0[rf], b0[cf], accM[rf][cf]);
                accC[rf][cf] = MFMA16(a0[rf], b1[cf], accC[rf][cf]);
                accC[rf][cf] = MFMA16(a1[rf], b0[cf], accC[rf][cf]);
            }
        __syncthreads();
    }
#pragma unroll
    for (int rf = 0; rf < 2; ++rf)
#pragma unroll
        for (int cf = 0; cf < 4; ++cf) {
            int col = col0 + cf * 16 + r;
            int head = col / DH;
            int c = col - head * DH;
            int ks = c >> 5, ki = c & 31;
#pragma unroll
            for (int j = 0; j < 4; ++j) {
                int row = row0 + wave * 32 + rf * 16 + g * 4 + j;
                float v = (accM[rf][cf][j] + accC[rf][cf][j] * INV_RSPLIT) * scl;
                f16 h0 = (f16)v;
                float res = (v - (float)h0) * RSPLIT;
                size_t addr = qkAddr(head, row, ks, ki);
                Qt0[addr] = h0;
                Qt1[addr] = (f16)res;
            }
        }
}

// ---------- LDS-tiled bf16 MFMA GEMM; mode 0 = fp32 flat, 2 = Vp tiled -------
__global__ __launch_bounds__(256) void gemm_bf16_lds(
    const ushort_t* __restrict__ A, const ushort_t* __restrict__ BT,
    const float* __restrict__ bias, void* __restrict__ C, int mode,
    int Nn, int K)
{
    __shared__ __align__(16) ushort_t As[128][40];
    __shared__ __align__(16) ushort_t Bs[64][40];
    const int tid = threadIdx.x;
    const int wave = tid >> 6, lane = tid & 63;
    const int r = lane & 15, g = lane >> 4;
    const int row0 = blockIdx.y * 128;
    const int col0 = blockIdx.x * 64;
    f32x4 acc[2][4] = {};
    for (int k0 = 0; k0 < K; k0 += 32) {
        for (int idx = tid; idx < 128 * 4; idx += 256) {
            int row = idx >> 2, c = idx & 3;
            *(bf16x8*)&As[row][c * 8] = *(const bf16x8*)(A + (size_t)(row0 + row) * K + k0 + c * 8);
        }
        for (int idx = tid; idx < 64 * 4; idx += 256) {
            int row = idx >> 2, c = idx & 3;
            *(bf16x8*)&Bs[row][c * 8] = *(const bf16x8*)(BT + (size_t)(col0 + row) * K + k0 + c * 8);
        }
        __syncthreads();
        bf16x8 a[2], b[4];
#pragma unroll
        for (int rf = 0; rf < 2; ++rf)
            a[rf] = *(const bf16x8*)&As[wave * 32 + rf * 16 + r][g * 8];
#pragma unroll
        for (int cf = 0; cf < 4; ++cf)
            b[cf] = *(const bf16x8*)&Bs[cf * 16 + r][g * 8];
#pragma unroll
        for (int rf = 0; rf < 2; ++rf)
#pragma unroll
            for (int cf = 0; cf < 4; ++cf)
                acc[rf][cf] = MFMABF(a[rf], b[cf], acc[rf][cf]);
        __syncthreads();
    }
#pragma unroll
    for (int rf = 0; rf < 2; ++rf)
#pragma unroll
        for (int cf = 0; cf < 4; ++cf) {
            int col = col0 + cf * 16 + r;
            float bv = bias ? bias[col] : 0.f;
#pragma unroll
            for (int j = 0; j < 4; ++j) {
                int row = row0 + wave * 32 + rf * 16 + g * 4 + j;
                float vv = acc[rf][cf][j] + bv;
                if (mode == 2) {
                    int head = col / DH;
                    int d = col - head * DH;
                    size_t addr = (((size_t)head * 128 + (row >> 5)) * 80 + d) * 32 + (row & 31);
                    ((ushort_t*)C)[addr] = f2b(vv);
                } else {
                    ((float*)C)[(size_t)row * Nn + col] = vv;
                }
            }
        }
}

// ---------- pass A: rowsum + PV, swapped-operand QK (no LDS transpose) -------
// MFMA(K_perm, Q): lane r holds S[row=r][cols g*8 + cfp*4 + j] in natural order,
// which IS the PV A-fragment layout. P never touches LDS.
__global__ __launch_bounds__(256) void rowsum_pv(
    const f16* __restrict__ Qt0, const f16* __restrict__ Qt1,
    const f16* __restrict__ Kt0, const f16* __restrict__ Kt1,
    const ushort_t* __restrict__ Vp,
    float* __restrict__ invs, ushort_t* __restrict__ otmpb)
{
    __shared__ __align__(16) f16 KL[2][6144];   // [plane][12 tiles of 512]
    const int tid = threadIdx.x;
    const int wv = tid >> 6, lane = tid & 63;
    const int r = lane & 15, g = lane >> 4;
    const int h = blockIdx.y;
    const int rowblk = blockIdx.x * 4 + wv;
    // Q fragments (used as the B operand of the swapped MFMA)
    f16x8 a0[3], a1[3];
#pragma unroll
    for (int ks = 0; ks < 3; ++ks) {
        size_t o = ((((size_t)h * 256 + rowblk) * 3 + ks) * 16) * 32 + r * 32 + g * 8;
        a0[ks] = *(const f16x8*)(Qt0 + o);
        a1[ks] = *(const f16x8*)(Qt1 + o);
    }
    // permuted per-lane K read columns: c32 = (r>>2)*8 + cfp*4 + (r&3)
    const int c32p0 = ((r >> 2) << 3) + (r & 3);
    float rs = 0.f;
    f32x4 oacc[5] = {};
    for (int ct = 0; ct < 64; ++ct) {
        __syncthreads();
        const size_t ctBase = ((size_t)h * 256 + ct * 4) * 1536;
#pragma unroll
        for (int s = 0; s < 6; ++s) {
            int wc = s * 4 + wv;             // 0..23 wave-chunks of 1024B
            int plane = wc >= 12;
            int cip = wc - plane * 12;
            const f16* src = (plane ? Kt1 : Kt0) + ctBase + cip * 512 + lane * 8;
            *(f16x8*)&KL[plane][cip * 512 + lane * 8] = *(const f16x8*)src;
        }
        __syncthreads();
        f32x4 accM[4] = {}, accC[4] = {};
#pragma unroll
        for (int ks = 0; ks < 3; ++ks) {
#pragma unroll
            for (int group = 0; group < 2; ++group) {
#pragma unroll
                for (int cfp = 0; cfp < 2; ++cfp) {
                    const int c32 = c32p0 + cfp * 4;
                    const int off = (((group * 2 + (c32 >> 4)) * 3 + ks) << 9)
                                  + ((c32 & 15) << 5) + (g << 3);
                    f16x8 b0 = *(const f16x8*)&KL[0][off];
                    f16x8 b1 = *(const f16x8*)&KL[1][off];
                    const int cf = group * 2 + cfp;
                    accM[cf] = MFMA16(b0, a0[ks], accM[cf]);
                    accC[cf] = MFMA16(b1, a0[ks], accC[cf]);
                    accC[cf] = MFMA16(b0, a1[ks], accC[cf]);
                }
            }
        }
        // exp -> rs + in-register bf16 pack -> PV
        const int kt0 = ct * 2;
#pragma unroll
        for (int group = 0; group < 2; ++group) {
            bf16x8 pa;
#pragma unroll
            for (int cfp = 0; cfp < 2; ++cfp) {
                const int cf = group * 2 + cfp;
#pragma unroll
                for (int j = 0; j < 4; ++j) {
                    float ev = __expf(accM[cf][j] + accC[cf][j] * INV_RSPLIT);
                    rs += ev;
                    pa[cfp * 4 + j] = (short)f2b(ev);
                }
            }
#pragma unroll
            for (int t = 0; t < 5; ++t) {
                int col = t * 16 + r;
                size_t vo = (((size_t)h * 128 + kt0 + group) * 80 + col) * 32 + g * 8;
                bf16x8 b = *(const bf16x8*)(Vp + vo);
                oacc[t] = MFMABF(pa, b, oacc[t]);
            }
        }
    }
    // rs is per-lane partial for q-row r; reduce over the 4 g-groups
    rs += __shfl_xor(rs, 16);
    rs += __shfl_xor(rs, 32);
    const float inv = 1.0f / rs;
    if (g == 0)
        invs[(size_t)h * NT + rowblk * 16 + r] = inv;
    float invq[4];
#pragma unroll
    for (int j = 0; j < 4; ++j) invq[j] = __shfl(inv, g * 4 + j);
#pragma unroll
    for (int t = 0; t < 5; ++t) {
        int col = t * 16 + r;
        if (col < DH) {
#pragma unroll
            for (int j = 0; j < 4; ++j) {
                int row = rowblk * 16 + g * 4 + j;
                otmpb[(size_t)row * DM + h * DH + col] = f2b(oacc[t][j] * invq[j]);
            }
        }
    }
}

// ---------- pass B: attn = (1/16) sum_h exp(s)*inv; write-once ---------------
__global__ __launch_bounds__(256) void attn_sum(
    const f16* __restrict__ Qt0, const f16* __restrict__ Qt1,
    const f16* __restrict__ Kt0, const f16* __restrict__ Kt1,
    const float* __restrict__ invs, float* __restrict__ attn)
{
    __shared__ __align__(16) f16 KL[4][6144];   // [pairhead*2+plane][12 tiles]
    const int tid = threadIdx.x;
    const int wr = tid >> 6, lane = tid & 63;
    const int r = lane & 15, g = lane >> 4;
    const int cs = blockIdx.x;
    const int rowblk = blockIdx.y * 4 + wr;
    const int row0 = rowblk * 16;
    for (int ct = 0; ct < 8; ++ct) {
        const int colbase = cs * 512 + ct * 64;
        const int cb0 = colbase >> 4;
        float aacc[4][4] = {};
        for (int hp = 0; hp < 8; ++hp) {
            __syncthreads();
#pragma unroll
            for (int s = 0; s < 12; ++s) {
                int wc = s * 4 + wr;            // 0..47 wave-chunks of 1024B
                int seg = wc / 12;              // hh*2 + plane
                int cip = wc - seg * 12;
                int hh = seg >> 1, pl = seg & 1;
                const f16* base = pl ? Kt1 : Kt0;
                size_t srcOff = ((size_t)(hp * 2 + hh) * 256 + cb0) * 1536
                              + cip * 512 + lane * 8;
                *(f16x8*)&KL[seg][cip * 512 + lane * 8] = *(const f16x8*)(base + srcOff);
            }
            __syncthreads();
#pragma unroll
            for (int hh2 = 0; hh2 < 2; ++hh2) {
                const int h = hp * 2 + hh2;
                f16x8 a0[3], a1[3];
#pragma unroll
                for (int ks = 0; ks < 3; ++ks) {
                    size_t o = ((((size_t)h * 256 + rowblk) * 3 + ks) * 16) * 32 + r * 32 + g * 8;
                    a0[ks] = *(const f16x8*)(Qt0 + o);
                    a1[ks] = *(const f16x8*)(Qt1 + o);
                }
                float vinv[4];
#pragma unroll
                for (int j = 0; j < 4; ++j)
                    vinv[j] = invs[(size_t)h * NT + row0 + g * 4 + j];
                f32x4 accM[4] = {}, accC[4] = {};
#pragma unroll
                for (int ks = 0; ks < 3; ++ks) {
#pragma unroll
                    for (int cf = 0; cf < 4; ++cf) {
                        f16x8 b0 = *(const f16x8*)&KL[hh2 * 2 + 0][(cf * 3 + ks) * 512 + r * 32 + g * 8];
                        f16x8 b1 = *(const f16x8*)&KL[hh2 * 2 + 1][(cf * 3 + ks) * 512 + r * 32 + g * 8];
                        accM[cf] = MFMA16(a0[ks], b0, accM[cf]);
                        accC[cf] = MFMA16(a0[ks], b1, accC[cf]);
                        accC[cf] = MFMA16(a1[ks], b0, accC[cf]);
                    }
                }
#pragma unroll
                for (int cf = 0; cf < 4; ++cf) {
#pragma unroll
                    for (int j = 0; j < 4; ++j) {
                        float p = __expf(accM[cf][j] + accC[cf][j] * INV_RSPLIT) * vinv[j];
                        aacc[cf][j] += p;
                    }
                }
            }
        }
        // write attn once (no rmw)
#pragma unroll
        for (int cf = 0; cf < 4; ++cf) {
#pragma unroll
            for (int j = 0; j < 4; ++j) {
                int row = row0 + g * 4 + j;
                attn[(size_t)row * NT + colbase + cf * 16 + r] = aacc[cf][j] * 0.0625f;
            }
        }
    }
}

// ---------- pagerank power iteration (fp32, unchanged) -----------------------
__global__ __launch_bounds__(256) void init_dist(float* __restrict__ d)
{
    int t = blockIdx.x * 256 + threadIdx.x;
    if (t < NT) d[t] = 1.0f / NT;
}

__global__ __launch_bounds__(256) void power_a(
    const float* __restrict__ attn, const float* __restrict__ din,
    float* __restrict__ part)
{
    int j = blockIdx.x * 256 + threadIdx.x;
    int i0 = blockIdx.y * 128;
    float acc = 0.f;
    for (int i = i0; i < i0 + 128; ++i)
        acc += din[i] * attn[(size_t)i * NT + j];
    part[(size_t)blockIdx.y * NT + j] = acc;
}

__global__ __launch_bounds__(256) void power_b(
    const float* __restrict__ part, float* __restrict__ dout)
{
    int j = blockIdx.x * 256 + threadIdx.x;
    float acc = 0.f;
    for (int ib = 0; ib < 32; ++ib) acc += part[(size_t)ib * NT + j];
    dout[j] = acc;
}

// ---------- top-k: tiled rank counting (deterministic int atomics) -----------
__global__ __launch_bounds__(256) void rank_count(
    const float* __restrict__ imp, int* __restrict__ rank, int* __restrict__ prank)
{
    __shared__ float sj[256];
    const int tid = threadIdx.x;
    const int jb = blockIdx.y * 256;
    sj[tid] = imp[jb + tid];
    __syncthreads();
    const int i = blockIdx.x * 256 + tid;
    const float mv = imp[i];
    int r = 0, rp = 0;
    for (int jj = 0; jj < 256; ++jj) {
        float vj = sj[jj];
        int j = jb + jj;
        int tie_low = (vj == mv) && (j < i);
        r  += (vj > mv) || tie_low;
        rp += (vj < mv) || tie_low;
    }
    atomicAdd(&rank[i], r);
    atomicAdd(&prank[i], rp);
}

__global__ __launch_bounds__(256) void scatter_topk2(
    const int* __restrict__ rank, const int* __restrict__ prank,
    float* __restrict__ out_imps, float* __restrict__ out_prune,
    int* __restrict__ imp_rows, int* __restrict__ prune_cols)
{
    __shared__ unsigned char fr[NT];
    __shared__ unsigned char fp[NT];
    __shared__ int sr[256], sp[256];
    const int tid = threadIdx.x;
    for (int t = tid; t < NT; t += 256) {
        fr[t] = rank[t] < KRET;
        fp[t] = prank[t] < NPR;
    }
    __syncthreads();
    const int base = tid * 16;
    int cr = 0, cp = 0;
#pragma unroll
    for (int e = 0; e < 16; ++e) { cr += fr[base + e]; cp += fp[base + e]; }
    sr[tid] = cr; sp[tid] = cp;
    __syncthreads();
    int pr = 0, pp = 0;
    for (int j = 0; j < tid; ++j) { pr += sr[j]; pp += sp[j]; }
#pragma unroll
    for (int e = 0; e < 16; ++e) {
        int i = base + e;
        if (fr[i]) { out_imps[pr] = (float)i; imp_rows[pr] = i; ++pr; }
        if (fp[i]) { out_prune[pp] = (float)i; prune_cols[pp] = i; ++pp; }
    }
}

__global__ __launch_bounds__(256) void argmax_part(
    const float* __restrict__ attn, const int* __restrict__ imp_rows,
    float* __restrict__ pbest, int* __restrict__ pbi)
{
    __shared__ int rows[CHUNK];
    const int tid = threadIdx.x;
    const int rc = blockIdx.y;
    const int r0 = rc * CHUNK;
    const int nr = min(KRET - r0, CHUNK);
    for (int t = tid; t < nr; t += 256) rows[t] = imp_rows[r0 + t];
    __syncthreads();
    const int j = blockIdx.x * 256 + tid;
    float best = -INFINITY;
    int bi = 0;
    for (int rr = 0; rr < nr; ++rr) {
        float val = attn[(size_t)rows[rr] * NT + j];
        if (val > best) { best = val; bi = r0 + rr; }
    }
    pbest[(size_t)rc * NT + j] = best;
    pbi[(size_t)rc * NT + j] = bi;
}

__global__ __launch_bounds__(256) void argmax_red(
    const float* __restrict__ pbest, const int* __restrict__ pbi,
    int* __restrict__ maxind)
{
    const int j = blockIdx.x * 256 + threadIdx.x;
    float best = -INFINITY;
    int bi = 0;
#pragma unroll
    for (int rc = 0; rc < 8; ++rc) {
        float val = pbest[(size_t)rc * NT + j];
        if (val > best) { best = val; bi = pbi[(size_t)rc * NT + j]; }
    }
    maxind[j] = bi;
}

__global__ __launch_bounds__(256) void finalize(
    const float* __restrict__ dist, const int* __restrict__ prune_cols,
    const int* __restrict__ maxind, float* __restrict__ out_imp,
    float* __restrict__ out_simi)
{
    int t = blockIdx.x * 256 + threadIdx.x;
    if (t < NT) out_imp[t] = dist[t];
    if (t < NPR) out_simi[t] = (float)maxind[prune_cols[t]];
}

extern "C" void kernel_launch(void* const* d_in, const int* in_sizes, int n_in,
                              void* d_out, int out_size, void* d_ws, size_t ws_size,
                              hipStream_t stream)
{
    const float* x  = (const float*)d_in[0];
    const float* Wq = (const float*)d_in[1];
    const float* Wk = (const float*)d_in[2];
    const float* Wv = (const float*)d_in[3];
    const float* Wo = (const float*)d_in[4];
    const float* bo = (const float*)d_in[5];
    float* out = (float*)d_out;

    const size_t QKT_EL = (size_t)NH * 256 * 3 * 16 * 32;   // 6.29M f16 per plane
    const size_t VP_EL  = (size_t)NH * 128 * 80 * 32;       // 5.24M bf16

    // ---- workspace layout (float units) ----
    float* ws = (float*)d_ws;
    size_t off = 0;
    float* attn = ws + off; off += (size_t)NT * NT;
    f16* Qt0 = (f16*)(ws + off); off += QKT_EL / 2;
    f16* Qt1 = (f16*)(ws + off); off += QKT_EL / 2;
    f16* Kt0 = (f16*)(ws + off); off += QKT_EL / 2;
    f16* Kt1 = (f16*)(ws + off); off += QKT_EL / 2;
    ushort_t* Vp = (ushort_t*)(ws + off); off += VP_EL / 2;
    size_t zero_floats = 4 * (QKT_EL / 2) + VP_EL / 2;      // Qt0..Vp contiguous
    ushort_t* otmpb = (ushort_t*)(ws + off); off += ((size_t)NT * DM) / 2;
    f16* X0 = (f16*)(ws + off); f16* X1 = X0 + (size_t)NT * DM; off += (size_t)NT * DM;
    f16* T0 = (f16*)(ws + off); f16* T1 = T0 + (size_t)DM * DM; off += (size_t)DM * DM;
    ushort_t* Wslot = (ushort_t*)(ws + off); off += ((size_t)DM * DM) / 2;
    float* invs    = ws + off; off += (size_t)NH * NT;
    float* pbest   = ws + off; off += 8 * NT;
    int*   pbi     = (int*)(ws + off); off += 8 * NT;
    float* dist0 = ws + off; off += NT;
    float* dist1 = ws + off; off += NT;
    float* partial = ws + off; off += 32 * NT;
    int* rank      = (int*)(ws + off); off += NT;
    int* prank     = (int*)(ws + off); off += NT;
    int* imp_rows  = (int*)(ws + off); off += 2048;
    int* prune_cols= (int*)(ws + off); off += 2560;
    int* maxind    = (int*)(ws + off); off += NT;

    // setup-only alias inside attn region (dead before attn_sum writes)
    ushort_t* xb = (ushort_t*)attn;

    // output layout
    float* out_out   = out;
    float* out_imp   = out + (size_t)NT * DM;
    float* out_imps  = out_imp + NT;
    float* out_prune = out_imps + KRET;
    float* out_simi  = out_prune + NPR;

    // ---- setup ----
    hipMemsetAsync(Qt0, 0, zero_floats * sizeof(float), stream);  // zero-pad tiles
    split_x<<<2048, 256, 0, stream>>>(x, X0, X1, xb, NT * DM);

    dim3 gT(DM / 32, DM / 32);
    dim3 gP(DM / 64, NT / 128);
    transposeW_split<<<gT, 256, 0, stream>>>(Wq, T0, T1, DM);
    proj_split3<<<gP, 256, 0, stream>>>(X0, X1, T0, T1, Qt0, Qt1, SCALE);
    transposeW_split<<<gT, 256, 0, stream>>>(Wk, T0, T1, DM);
    proj_split3<<<gP, 256, 0, stream>>>(X0, X1, T0, T1, Kt0, Kt1, 1.0f);

    transposeW_bf16<<<gT, 256, 0, stream>>>(Wv, Wslot, DM);
    gemm_bf16_lds<<<gP, 256, 0, stream>>>(xb, Wslot, nullptr, Vp, 2, DM, DM);

    // ---- pass A: rowsums + PV (swapped-operand QK, register-resident P) ----
    rowsum_pv<<<dim3(NT / 64, NH), 256, 0, stream>>>(Qt0, Qt1, Kt0, Kt1, Vp,
                                                     invs, otmpb);

    // ---- pass B: attn head-sum, single launch, write-once ----
    attn_sum<<<dim3(CSB, NT / 64), 256, 0, stream>>>(Qt0, Qt1, Kt0, Kt1, invs, attn);

    // ---- output projection ----
    transposeW_bf16<<<gT, 256, 0, stream>>>(Wo, Wslot, DM);
    gemm_bf16_lds<<<gP, 256, 0, stream>>>(otmpb, Wslot, bo, out_out, 0, DM, DM);

    // ---- pagerank ----
    init_dist<<<16, 256, 0, stream>>>(dist0);
    float* da = dist0;
    float* db = dist1;
    for (int it = 0; it < 5; ++it) {
        power_a<<<dim3(16, 32), 256, 0, stream>>>(attn, da, partial);
        power_b<<<16, 256, 0, stream>>>(partial, db);
        float* t = da; da = db; db = t;
    }

    // ---- top-k ----
    hipMemsetAsync(rank, 0, 2 * NT * sizeof(int), stream);
    rank_count<<<dim3(16, 16), 256, 0, stream>>>(da, rank, prank);
    scatter_topk2<<<1, 256, 0, stream>>>(rank, prank, out_imps, out_prune,
                                         imp_rows, prune_cols);
    argmax_part<<<dim3(16, 8), 256, 0, stream>>>(attn, imp_rows, pbest, pbi);
    argmax_red<<<16, 256, 0, stream>>>(pbest, pbi, maxind);
    finalize<<<16, 256, 0, stream>>>(da, prune_cols, maxind, out_imp, out_simi);
}

// Round 12
// 1064.213 us; speedup vs baseline: 1.3687x; 1.0675x over previous
//
#include <hip/hip_runtime.h>
#include <math.h>

#define NT 4096
#define DM 1152
#define NH 16
#define DH 72
#define KRET 1638
#define NPR (NT - KRET)
#define CSB 8
#define CHUNK 205
#define SCALE 0.11785113019775793f
#define RSPLIT 2048.0f
#define INV_RSPLIT 4.8828125e-4f

typedef __attribute__((ext_vector_type(8))) short bf16x8;
typedef _Float16 f16;
typedef __attribute__((ext_vector_type(8))) _Float16 f16x8;
typedef __attribute__((ext_vector_type(4))) float f32x4;
typedef unsigned short ushort_t;

#define MFMA16(a, b, c) __builtin_amdgcn_mfma_f32_16x16x32_f16(a, b, c, 0, 0, 0)
#define MFMABF(a, b, c) __builtin_amdgcn_mfma_f32_16x16x32_bf16(a, b, c, 0, 0, 0)

__device__ inline ushort_t f2b(float f) {
    union { float f; unsigned int u; } v; v.f = f;
    unsigned int u = v.u;
    return (ushort_t)((u + 0x7FFFu + ((u >> 16) & 1u)) >> 16);
}

// tiled Q/K address: [NH][rowblk 256][ks 3][r 16][ki 32]
__device__ inline size_t qkAddr(int h, int row, int ks, int ki) {
    return ((((size_t)h * 256 + (row >> 4)) * 3 + ks) * 16 + (row & 15)) * 32 + ki;
}

// ---------- split x into fp16 hi/lo(x2048) planes + bf16 copy ----------------
__global__ __launch_bounds__(256) void split_x(
    const float* __restrict__ in, f16* __restrict__ x0, f16* __restrict__ x1,
    ushort_t* __restrict__ xb, int nElem)
{
    int i = blockIdx.x * 256 + threadIdx.x;
    int stride = gridDim.x * 256;
    for (; i < nElem; i += stride) {
        float v = in[i];
        f16 h0 = (f16)v;
        float res = (v - (float)h0) * RSPLIT;
        x0[i] = h0;
        x1[i] = (f16)res;
        xb[i] = f2b(v);
    }
}

__global__ __launch_bounds__(256) void transposeW_split(
    const float* __restrict__ W, f16* __restrict__ T0, f16* __restrict__ T1, int n)
{
    __shared__ float t[32][33];
    int bx = blockIdx.x * 32, by = blockIdx.y * 32;
    int tx = threadIdx.x & 31, ty = threadIdx.x >> 5;
    for (int i = ty; i < 32; i += 8)
        t[i][tx] = W[(size_t)(by + i) * n + bx + tx];
    __syncthreads();
    for (int i = ty; i < 32; i += 8) {
        float v = t[tx][i];
        f16 h0 = (f16)v;
        float res = (v - (float)h0) * RSPLIT;
        T0[(size_t)(bx + i) * n + by + tx] = h0;
        T1[(size_t)(bx + i) * n + by + tx] = (f16)res;
    }
}

__global__ __launch_bounds__(256) void transposeW_bf16(
    const float* __restrict__ W, ushort_t* __restrict__ WT, int n)
{
    __shared__ ushort_t t[32][33];
    int bx = blockIdx.x * 32, by = blockIdx.y * 32;
    int tx = threadIdx.x & 31, ty = threadIdx.x >> 5;
    for (int i = ty; i < 32; i += 8)
        t[i][tx] = f2b(W[(size_t)(by + i) * n + bx + tx]);
    __syncthreads();
    for (int i = ty; i < 32; i += 8)
        WT[(size_t)(bx + i) * n + by + tx] = t[tx][i];
}

// ---------- LDS-tiled split projection -> MFMA-tiled per-head output ---------
__global__ __launch_bounds__(256) void proj_split3(
    const f16* __restrict__ A0, const f16* __restrict__ A1,
    const f16* __restrict__ B0, const f16* __restrict__ B1,
    f16* __restrict__ Qt0, f16* __restrict__ Qt1, float scl)
{
    __shared__ __align__(16) f16 As0[128][40];
    __shared__ __align__(16) f16 As1[128][40];
    __shared__ __align__(16) f16 Bs0[64][40];
    __shared__ __align__(16) f16 Bs1[64][40];
    const int tid = threadIdx.x;
    const int wave = tid >> 6, lane = tid & 63;
    const int r = lane & 15, g = lane >> 4;
    const int row0 = blockIdx.y * 128;
    const int col0 = blockIdx.x * 64;
    f32x4 accM[2][4] = {}, accC[2][4] = {};
    for (int k0 = 0; k0 < DM; k0 += 32) {
        for (int idx = tid; idx < 128 * 4; idx += 256) {
            int row = idx >> 2, c = idx & 3;
            size_t src = (size_t)(row0 + row) * DM + k0 + c * 8;
            *(f16x8*)&As0[row][c * 8] = *(const f16x8*)(A0 + src);
            *(f16x8*)&As1[row][c * 8] = *(const f16x8*)(A1 + src);
        }
        for (int idx = tid; idx < 64 * 4; idx += 256) {
            int row = idx >> 2, c = idx & 3;
            size_t src = (size_t)(col0 + row) * DM + k0 + c * 8;
            *(f16x8*)&Bs0[row][c * 8] = *(const f16x8*)(B0 + src);
            *(f16x8*)&Bs1[row][c * 8] = *(const f16x8*)(B1 + src);
        }
        __syncthreads();
        f16x8 a0[2], a1[2], b0[4], b1[4];
#pragma unroll
        for (int rf = 0; rf < 2; ++rf) {
            a0[rf] = *(const f16x8*)&As0[wave * 32 + rf * 16 + r][g * 8];
            a1[rf] = *(const f16x8*)&As1[wave * 32 + rf * 16 + r][g * 8];
        }
#pragma unroll
        for (int cf = 0; cf < 4; ++cf) {
            b0[cf] = *(const f16x8*)&Bs0[cf * 16 + r][g * 8];
            b1[cf] = *(const f16x8*)&Bs1[cf * 16 + r][g * 8];
        }
#pragma unroll
        for (int rf = 0; rf < 2; ++rf)
#pragma unroll
            for (int cf = 0; cf < 4; ++cf) {
                accM[rf][cf] = MFMA16(a0[rf], b0[cf], accM[rf][cf]);
                accC[rf][cf] = MFMA16(a0[rf], b1[cf], accC[rf][cf]);
                accC[rf][cf] = MFMA16(a1[rf], b0[cf], accC[rf][cf]);
            }
        __syncthreads();
    }
#pragma unroll
    for (int rf = 0; rf < 2; ++rf)
#pragma unroll
        for (int cf = 0; cf < 4; ++cf) {
            int col = col0 + cf * 16 + r;
            int head = col / DH;
            int c = col - head * DH;
            int ks = c >> 5, ki = c & 31;
#pragma unroll
            for (int j = 0; j < 4; ++j) {
                int row = row0 + wave * 32 + rf * 16 + g * 4 + j;
                float v = (accM[rf][cf][j] + accC[rf][cf][j] * INV_RSPLIT) * scl;
                f16 h0 = (f16)v;
                float res = (v - (float)h0) * RSPLIT;
                size_t addr = qkAddr(head, row, ks, ki);
                Qt0[addr] = h0;
                Qt1[addr] = (f16)res;
            }
        }
}

// ---------- LDS-tiled bf16 MFMA GEMM; mode 0 = fp32 flat, 2 = Vp tiled -------
__global__ __launch_bounds__(256) void gemm_bf16_lds(
    const ushort_t* __restrict__ A, const ushort_t* __restrict__ BT,
    const float* __restrict__ bias, void* __restrict__ C, int mode,
    int Nn, int K)
{
    __shared__ __align__(16) ushort_t As[128][40];
    __shared__ __align__(16) ushort_t Bs[64][40];
    const int tid = threadIdx.x;
    const int wave = tid >> 6, lane = tid & 63;
    const int r = lane & 15, g = lane >> 4;
    const int row0 = blockIdx.y * 128;
    const int col0 = blockIdx.x * 64;
    f32x4 acc[2][4] = {};
    for (int k0 = 0; k0 < K; k0 += 32) {
        for (int idx = tid; idx < 128 * 4; idx += 256) {
            int row = idx >> 2, c = idx & 3;
            *(bf16x8*)&As[row][c * 8] = *(const bf16x8*)(A + (size_t)(row0 + row) * K + k0 + c * 8);
        }
        for (int idx = tid; idx < 64 * 4; idx += 256) {
            int row = idx >> 2, c = idx & 3;
            *(bf16x8*)&Bs[row][c * 8] = *(const bf16x8*)(BT + (size_t)(col0 + row) * K + k0 + c * 8);
        }
        __syncthreads();
        bf16x8 a[2], b[4];
#pragma unroll
        for (int rf = 0; rf < 2; ++rf)
            a[rf] = *(const bf16x8*)&As[wave * 32 + rf * 16 + r][g * 8];
#pragma unroll
        for (int cf = 0; cf < 4; ++cf)
            b[cf] = *(const bf16x8*)&Bs[cf * 16 + r][g * 8];
#pragma unroll
        for (int rf = 0; rf < 2; ++rf)
#pragma unroll
            for (int cf = 0; cf < 4; ++cf)
                acc[rf][cf] = MFMABF(a[rf], b[cf], acc[rf][cf]);
        __syncthreads();
    }
#pragma unroll
    for (int rf = 0; rf < 2; ++rf)
#pragma unroll
        for (int cf = 0; cf < 4; ++cf) {
            int col = col0 + cf * 16 + r;
            float bv = bias ? bias[col] : 0.f;
#pragma unroll
            for (int j = 0; j < 4; ++j) {
                int row = row0 + wave * 32 + rf * 16 + g * 4 + j;
                float vv = acc[rf][cf][j] + bv;
                if (mode == 2) {
                    int head = col / DH;
                    int d = col - head * DH;
                    size_t addr = (((size_t)head * 128 + (row >> 5)) * 80 + d) * 32 + (row & 31);
                    ((ushort_t*)C)[addr] = f2b(vv);
                } else {
                    ((float*)C)[(size_t)row * Nn + col] = vv;
                }
            }
        }
}

// ---------- pass A: rowsum + PV, swapped-operand QK (no LDS transpose) -------
__global__ __launch_bounds__(256) void rowsum_pv(
    const f16* __restrict__ Qt0, const f16* __restrict__ Qt1,
    const f16* __restrict__ Kt0, const f16* __restrict__ Kt1,
    const ushort_t* __restrict__ Vp,
    float* __restrict__ invs, ushort_t* __restrict__ otmpb)
{
    __shared__ __align__(16) f16 KL[2][6144];   // [plane][12 tiles of 512]
    const int tid = threadIdx.x;
    const int wv = tid >> 6, lane = tid & 63;
    const int r = lane & 15, g = lane >> 4;
    const int h = blockIdx.y;
    const int rowblk = blockIdx.x * 4 + wv;
    // Q fragments (used as the B operand of the swapped MFMA)
    f16x8 a0[3], a1[3];
#pragma unroll
    for (int ks = 0; ks < 3; ++ks) {
        size_t o = ((((size_t)h * 256 + rowblk) * 3 + ks) * 16) * 32 + r * 32 + g * 8;
        a0[ks] = *(const f16x8*)(Qt0 + o);
        a1[ks] = *(const f16x8*)(Qt1 + o);
    }
    // permuted per-lane K read columns: c32 = (r>>2)*8 + cfp*4 + (r&3)
    const int c32p0 = ((r >> 2) << 3) + (r & 3);
    float rs = 0.f;
    f32x4 oacc[5] = {};
    for (int ct = 0; ct < 64; ++ct) {
        __syncthreads();
        const size_t ctBase = ((size_t)h * 256 + ct * 4) * 1536;
#pragma unroll
        for (int s = 0; s < 6; ++s) {
            int wc = s * 4 + wv;             // 0..23 wave-chunks of 1024B
            int plane = wc >= 12;
            int cip = wc - plane * 12;
            const f16* src = (plane ? Kt1 : Kt0) + ctBase + cip * 512 + lane * 8;
            *(f16x8*)&KL[plane][cip * 512 + lane * 8] = *(const f16x8*)src;
        }
        __syncthreads();
        f32x4 accM[4] = {}, accC[4] = {};
#pragma unroll
        for (int ks = 0; ks < 3; ++ks) {
#pragma unroll
            for (int group = 0; group < 2; ++group) {
#pragma unroll
                for (int cfp = 0; cfp < 2; ++cfp) {
                    const int c32 = c32p0 + cfp * 4;
                    const int off = (((group * 2 + (c32 >> 4)) * 3 + ks) << 9)
                                  + ((c32 & 15) << 5) + (g << 3);
                    f16x8 b0 = *(const f16x8*)&KL[0][off];
                    f16x8 b1 = *(const f16x8*)&KL[1][off];
                    const int cf = group * 2 + cfp;
                    accM[cf] = MFMA16(b0, a0[ks], accM[cf]);
                    accC[cf] = MFMA16(b1, a0[ks], accC[cf]);
                    accC[cf] = MFMA16(b0, a1[ks], accC[cf]);
                }
            }
        }
        // exp -> rs + in-register bf16 pack -> PV
        const int kt0 = ct * 2;
#pragma unroll
        for (int group = 0; group < 2; ++group) {
            bf16x8 pa;
#pragma unroll
            for (int cfp = 0; cfp < 2; ++cfp) {
                const int cf = group * 2 + cfp;
#pragma unroll
                for (int j = 0; j < 4; ++j) {
                    float ev = __expf(accM[cf][j] + accC[cf][j] * INV_RSPLIT);
                    rs += ev;
                    pa[cfp * 4 + j] = (short)f2b(ev);
                }
            }
#pragma unroll
            for (int t = 0; t < 5; ++t) {
                int col = t * 16 + r;
                size_t vo = (((size_t)h * 128 + kt0 + group) * 80 + col) * 32 + g * 8;
                bf16x8 b = *(const bf16x8*)(Vp + vo);
                oacc[t] = MFMABF(pa, b, oacc[t]);
            }
        }
    }
    // rs is per-lane partial for q-row r; reduce over the 4 g-groups
    rs += __shfl_xor(rs, 16);
    rs += __shfl_xor(rs, 32);
    const float inv = 1.0f / rs;
    if (g == 0)
        invs[(size_t)h * NT + rowblk * 16 + r] = inv;
    float invq[4];
#pragma unroll
    for (int j = 0; j < 4; ++j) invq[j] = __shfl(inv, g * 4 + j);
#pragma unroll
    for (int t = 0; t < 5; ++t) {
        int col = t * 16 + r;
        if (col < DH) {
#pragma unroll
            for (int j = 0; j < 4; ++j) {
                int row = rowblk * 16 + g * 4 + j;
                otmpb[(size_t)row * DM + h * DH + col] = f2b(oacc[t][j] * invq[j]);
            }
        }
    }
}

// ---------- pass B: attn = (1/16) sum_h exp(s)*inv; head-outer, write-once ---
// grid (CSB, NT/64). Q loaded once per head; attn row-tile lives in registers.
__global__ __launch_bounds__(256) void attn_sum(
    const f16* __restrict__ Qt0, const f16* __restrict__ Qt1,
    const f16* __restrict__ Kt0, const f16* __restrict__ Kt1,
    const float* __restrict__ invs, float* __restrict__ attn)
{
    __shared__ __align__(16) f16 KL[2][6144];   // [plane][12 tiles of 512]
    const int tid = threadIdx.x;
    const int wr = tid >> 6, lane = tid & 63;
    const int r = lane & 15, g = lane >> 4;
    const int cs = blockIdx.x;
    const int rowblk = blockIdx.y * 4 + wr;
    const int row0 = rowblk * 16;
    const int cb0 = cs * 32;                    // colblk base for this col-slice
    float aacc[8][4][4] = {};                   // [ct][cf][j]
    for (int h = 0; h < NH; ++h) {
        // Q fragments once per head
        f16x8 a0[3], a1[3];
#pragma unroll
        for (int ks = 0; ks < 3; ++ks) {
            size_t o = ((((size_t)h * 256 + rowblk) * 3 + ks) * 16) * 32 + r * 32 + g * 8;
            a0[ks] = *(const f16x8*)(Qt0 + o);
            a1[ks] = *(const f16x8*)(Qt1 + o);
        }
        float vinv[4];
#pragma unroll
        for (int j = 0; j < 4; ++j)
            vinv[j] = invs[(size_t)h * NT + row0 + g * 4 + j];
#pragma unroll
        for (int ct = 0; ct < 8; ++ct) {
            __syncthreads();
            const size_t ctBase = ((size_t)h * 256 + cb0 + ct * 4) * 1536;
#pragma unroll
            for (int s = 0; s < 6; ++s) {
                int wc = s * 4 + wr;            // 0..23 wave-chunks of 1024B
                int plane = wc >= 12;
                int cip = wc - plane * 12;
                const f16* src = (plane ? Kt1 : Kt0) + ctBase + cip * 512 + lane * 8;
                *(f16x8*)&KL[plane][cip * 512 + lane * 8] = *(const f16x8*)src;
            }
            __syncthreads();
            f32x4 accM[4] = {}, accC[4] = {};
#pragma unroll
            for (int ks = 0; ks < 3; ++ks) {
#pragma unroll
                for (int cf = 0; cf < 4; ++cf) {
                    f16x8 b0 = *(const f16x8*)&KL[0][(cf * 3 + ks) * 512 + r * 32 + g * 8];
                    f16x8 b1 = *(const f16x8*)&KL[1][(cf * 3 + ks) * 512 + r * 32 + g * 8];
                    accM[cf] = MFMA16(a0[ks], b0, accM[cf]);
                    accC[cf] = MFMA16(a0[ks], b1, accC[cf]);
                    accC[cf] = MFMA16(a1[ks], b0, accC[cf]);
                }
            }
#pragma unroll
            for (int cf = 0; cf < 4; ++cf) {
#pragma unroll
                for (int j = 0; j < 4; ++j) {
                    float p = __expf(accM[cf][j] + accC[cf][j] * INV_RSPLIT) * vinv[j];
                    aacc[ct][cf][j] += p;
                }
            }
        }
    }
    // write attn once (no rmw)
#pragma unroll
    for (int ct = 0; ct < 8; ++ct) {
        const int colbase = cs * 512 + ct * 64;
#pragma unroll
        for (int cf = 0; cf < 4; ++cf) {
#pragma unroll
            for (int j = 0; j < 4; ++j) {
                int row = row0 + g * 4 + j;
                attn[(size_t)row * NT + colbase + cf * 16 + r] = aacc[ct][cf][j] * 0.0625f;
            }
        }
    }
}

// ---------- pagerank power iteration (fp32, unchanged) -----------------------
__global__ __launch_bounds__(256) void init_dist(float* __restrict__ d)
{
    int t = blockIdx.x * 256 + threadIdx.x;
    if (t < NT) d[t] = 1.0f / NT;
}

__global__ __launch_bounds__(256) void power_a(
    const float* __restrict__ attn, const float* __restrict__ din,
    float* __restrict__ part)
{
    int j = blockIdx.x * 256 + threadIdx.x;
    int i0 = blockIdx.y * 128;
    float acc = 0.f;
    for (int i = i0; i < i0 + 128; ++i)
        acc += din[i] * attn[(size_t)i * NT + j];
    part[(size_t)blockIdx.y * NT + j] = acc;
}

__global__ __launch_bounds__(256) void power_b(
    const float* __restrict__ part, float* __restrict__ dout)
{
    int j = blockIdx.x * 256 + threadIdx.x;
    float acc = 0.f;
    for (int ib = 0; ib < 32; ++ib) acc += part[(size_t)ib * NT + j];
    dout[j] = acc;
}

// ---------- top-k: tiled rank counting (deterministic int atomics) -----------
__global__ __launch_bounds__(256) void rank_count(
    const float* __restrict__ imp, int* __restrict__ rank, int* __restrict__ prank)
{
    __shared__ float sj[256];
    const int tid = threadIdx.x;
    const int jb = blockIdx.y * 256;
    sj[tid] = imp[jb + tid];
    __syncthreads();
    const int i = blockIdx.x * 256 + tid;
    const float mv = imp[i];
    int r = 0, rp = 0;
    for (int jj = 0; jj < 256; ++jj) {
        float vj = sj[jj];
        int j = jb + jj;
        int tie_low = (vj == mv) && (j < i);
        r  += (vj > mv) || tie_low;
        rp += (vj < mv) || tie_low;
    }
    atomicAdd(&rank[i], r);
    atomicAdd(&prank[i], rp);
}

__global__ __launch_bounds__(256) void scatter_topk2(
    const int* __restrict__ rank, const int* __restrict__ prank,
    float* __restrict__ out_imps, float* __restrict__ out_prune,
    int* __restrict__ imp_rows, int* __restrict__ prune_cols)
{
    __shared__ unsigned char fr[NT];
    __shared__ unsigned char fp[NT];
    __shared__ int sr[256], sp[256];
    const int tid = threadIdx.x;
    for (int t = tid; t < NT; t += 256) {
        fr[t] = rank[t] < KRET;
        fp[t] = prank[t] < NPR;
    }
    __syncthreads();
    const int base = tid * 16;
    int cr = 0, cp = 0;
#pragma unroll
    for (int e = 0; e < 16; ++e) { cr += fr[base + e]; cp += fp[base + e]; }
    sr[tid] = cr; sp[tid] = cp;
    __syncthreads();
    int pr = 0, pp = 0;
    for (int j = 0; j < tid; ++j) { pr += sr[j]; pp += sp[j]; }
#pragma unroll
    for (int e = 0; e < 16; ++e) {
        int i = base + e;
        if (fr[i]) { out_imps[pr] = (float)i; imp_rows[pr] = i; ++pr; }
        if (fp[i]) { out_prune[pp] = (float)i; prune_cols[pp] = i; ++pp; }
    }
}

__global__ __launch_bounds__(256) void argmax_part(
    const float* __restrict__ attn, const int* __restrict__ imp_rows,
    float* __restrict__ pbest, int* __restrict__ pbi)
{
    __shared__ int rows[CHUNK];
    const int tid = threadIdx.x;
    const int rc = blockIdx.y;
    const int r0 = rc * CHUNK;
    const int nr = min(KRET - r0, CHUNK);
    for (int t = tid; t < nr; t += 256) rows[t] = imp_rows[r0 + t];
    __syncthreads();
    const int j = blockIdx.x * 256 + tid;
    float best = -INFINITY;
    int bi = 0;
    for (int rr = 0; rr < nr; ++rr) {
        float val = attn[(size_t)rows[rr] * NT + j];
        if (val > best) { best = val; bi = r0 + rr; }
    }
    pbest[(size_t)rc * NT + j] = best;
    pbi[(size_t)rc * NT + j] = bi;
}

__global__ __launch_bounds__(256) void argmax_red(
    const float* __restrict__ pbest, const int* __restrict__ pbi,
    int* __restrict__ maxind)
{
    const int j = blockIdx.x * 256 + threadIdx.x;
    float best = -INFINITY;
    int bi = 0;
#pragma unroll
    for (int rc = 0; rc < 8; ++rc) {
        float val = pbest[(size_t)rc * NT + j];
        if (val > best) { best = val; bi = pbi[(size_t)rc * NT + j]; }
    }
    maxind[j] = bi;
}

__global__ __launch_bounds__(256) void finalize(
    const float* __restrict__ dist, const int* __restrict__ prune_cols,
    const int* __restrict__ maxind, float* __restrict__ out_imp,
    float* __restrict__ out_simi)
{
    int t = blockIdx.x * 256 + threadIdx.x;
    if (t < NT) out_imp[t] = dist[t];
    if (t < NPR) out_simi[t] = (float)maxind[prune_cols[t]];
}

extern "C" void kernel_launch(void* const* d_in, const int* in_sizes, int n_in,
                              void* d_out, int out_size, void* d_ws, size_t ws_size,
                              hipStream_t stream)
{
    const float* x  = (const float*)d_in[0];
    const float* Wq = (const float*)d_in[1];
    const float* Wk = (const float*)d_in[2];
    const float* Wv = (const float*)d_in[3];
    const float* Wo = (const float*)d_in[4];
    const float* bo = (const float*)d_in[5];
    float* out = (float*)d_out;

    const size_t QKT_EL = (size_t)NH * 256 * 3 * 16 * 32;   // 6.29M f16 per plane
    const size_t VP_EL  = (size_t)NH * 128 * 80 * 32;       // 5.24M bf16

    // ---- workspace layout (float units) ----
    float* ws = (float*)d_ws;
    size_t off = 0;
    float* attn = ws + off; off += (size_t)NT * NT;
    f16* Qt0 = (f16*)(ws + off); off += QKT_EL / 2;
    f16* Qt1 = (f16*)(ws + off); off += QKT_EL / 2;
    f16* Kt0 = (f16*)(ws + off); off += QKT_EL / 2;
    f16* Kt1 = (f16*)(ws + off); off += QKT_EL / 2;
    ushort_t* Vp = (ushort_t*)(ws + off); off += VP_EL / 2;
    size_t zero_floats = 4 * (QKT_EL / 2) + VP_EL / 2;      // Qt0..Vp contiguous
    ushort_t* otmpb = (ushort_t*)(ws + off); off += ((size_t)NT * DM) / 2;
    f16* X0 = (f16*)(ws + off); f16* X1 = X0 + (size_t)NT * DM; off += (size_t)NT * DM;
    f16* T0 = (f16*)(ws + off); f16* T1 = T0 + (size_t)DM * DM; off += (size_t)DM * DM;
    ushort_t* Wslot = (ushort_t*)(ws + off); off += ((size_t)DM * DM) / 2;
    float* invs    = ws + off; off += (size_t)NH * NT;
    float* pbest   = ws + off; off += 8 * NT;
    int*   pbi     = (int*)(ws + off); off += 8 * NT;
    float* dist0 = ws + off; off += NT;
    float* dist1 = ws + off; off += NT;
    float* partial = ws + off; off += 32 * NT;
    int* rank      = (int*)(ws + off); off += NT;
    int* prank     = (int*)(ws + off); off += NT;
    int* imp_rows  = (int*)(ws + off); off += 2048;
    int* prune_cols= (int*)(ws + off); off += 2560;
    int* maxind    = (int*)(ws + off); off += NT;

    // setup-only alias inside attn region (dead before attn_sum writes)
    ushort_t* xb = (ushort_t*)attn;

    // output layout
    float* out_out   = out;
    float* out_imp   = out + (size_t)NT * DM;
    float* out_imps  = out_imp + NT;
    float* out_prune = out_imps + KRET;
    float* out_simi  = out_prune + NPR;

    // ---- setup ----
    hipMemsetAsync(Qt0, 0, zero_floats * sizeof(float), stream);  // zero-pad tiles
    split_x<<<2048, 256, 0, stream>>>(x, X0, X1, xb, NT * DM);

    dim3 gT(DM / 32, DM / 32);
    dim3 gP(DM / 64, NT / 128);
    transposeW_split<<<gT, 256, 0, stream>>>(Wq, T0, T1, DM);
    proj_split3<<<gP, 256, 0, stream>>>(X0, X1, T0, T1, Qt0, Qt1, SCALE);
    transposeW_split<<<gT, 256, 0, stream>>>(Wk, T0, T1, DM);
    proj_split3<<<gP, 256, 0, stream>>>(X0, X1, T0, T1, Kt0, Kt1, 1.0f);

    transposeW_bf16<<<gT, 256, 0, stream>>>(Wv, Wslot, DM);
    gemm_bf16_lds<<<gP, 256, 0, stream>>>(xb, Wslot, nullptr, Vp, 2, DM, DM);

    // ---- pass A: rowsums + PV (swapped-operand QK, register-resident P) ----
    rowsum_pv<<<dim3(NT / 64, NH), 256, 0, stream>>>(Qt0, Qt1, Kt0, Kt1, Vp,
                                                     invs, otmpb);

    // ---- pass B: attn head-sum, single launch, head-outer, write-once ----
    attn_sum<<<dim3(CSB, NT / 64), 256, 0, stream>>>(Qt0, Qt1, Kt0, Kt1, invs, attn);

    // ---- output projection ----
    transposeW_bf16<<<gT, 256, 0, stream>>>(Wo, Wslot, DM);
    gemm_bf16_lds<<<gP, 256, 0, stream>>>(otmpb, Wslot, bo, out_out, 0, DM, DM);

    // ---- pagerank ----
    init_dist<<<16, 256, 0, stream>>>(dist0);
    float* da = dist0;
    float* db = dist1;
    for (int it = 0; it < 5; ++it) {
        power_a<<<dim3(16, 32), 256, 0, stream>>>(attn, da, partial);
        power_b<<<16, 256, 0, stream>>>(partial, db);
        float* t = da; da = db; db = t;
    }

    // ---- top-k ----
    hipMemsetAsync(rank, 0, 2 * NT * sizeof(int), stream);
    rank_count<<<dim3(16, 16), 256, 0, stream>>>(da, rank, prank);
    scatter_topk2<<<1, 256, 0, stream>>>(rank, prank, out_imps, out_prune,
                                         imp_rows, prune_cols);
    argmax_part<<<dim3(16, 8), 256, 0, stream>>>(attn, imp_rows, pbest, pbi);
    argmax_red<<<16, 256, 0, stream>>>(pbest, pbi, maxind);
    finalize<<<16, 256, 0, stream>>>(da, prune_cols, maxind, out_imp, out_simi);
}